// Round 5
// baseline (2875.716 us; speedup 1.0000x reference)
//
#include <hip/hip_runtime.h>
#include <hip/hip_bf16.h>

#define D 128
#define NGRAPH 64
#define SCAN_EPB 2048   // elements per scan block (256 thr * 8)
#define CHUNK 4096      // edges staged in LDS per block in k_fill2
#define BSHIFT 13       // dst-bucket = dst >> 13 (8192 nodes/bucket, ~1MB csr window)
#define SHSHIFT 13      // src-shard = src >> 13 (13 shards of 8192 nodes, 2MB bf16 each)
#define SHPAD 16        // counters per node (13 shards padded to 16)
#define APBLK 512       // blocks in k_agg_pool (2/CU)
#define APWAVES (APBLK * 16)

__device__ __forceinline__ unsigned short f2bf(float f) {
    union { float f; unsigned int i; } u; u.f = f;
    unsigned int r = u.i + 0x7fffu + ((u.i >> 16) & 1u);   // round-to-nearest-even
    return (unsigned short)(r >> 16);
}
__device__ __forceinline__ float2 bf2_to_f2(unsigned int u) {
    union { unsigned int i; float f; } a, b;
    a.i = u << 16;            // low ushort  = element 0
    b.i = u & 0xffff0000u;    // high ushort = element 1
    return make_float2(a.f, b.f);
}

// ---------------- CSR build ----------------

__global__ __launch_bounds__(256) void k_count(const int* __restrict__ src,
                                               const int* __restrict__ dst,
                                               int* __restrict__ deg,
                                               unsigned char* __restrict__ rank, int E) {
    int i = (blockIdx.x * blockDim.x + threadIdx.x) * 4;
    int stride = gridDim.x * blockDim.x * 4;
    for (; i < E; i += stride) {
        if (i + 3 < E) {
            int4 d4 = *(const int4*)&dst[i];
            int4 s4 = *(const int4*)&src[i];
            int r0 = atomicAdd(&deg[(d4.x << 4) | (s4.x >> SHSHIFT)], 1);
            int r1 = atomicAdd(&deg[(d4.y << 4) | (s4.y >> SHSHIFT)], 1);
            int r2 = atomicAdd(&deg[(d4.z << 4) | (s4.z >> SHSHIFT)], 1);
            int r3 = atomicAdd(&deg[(d4.w << 4) | (s4.w >> SHSHIFT)], 1);
            unsigned pack = (unsigned)(r0 & 0xff) | ((unsigned)(r1 & 0xff) << 8) |
                            ((unsigned)(r2 & 0xff) << 16) | ((unsigned)(r3 & 0xff) << 24);
            __builtin_nontemporal_store(pack, (unsigned*)&rank[i]);
        } else {
            for (int j = i; j < E; ++j) {
                int d = dst[j], s = src[j];
                int r = atomicAdd(&deg[(d << 4) | (s >> SHSHIFT)], 1);
                rank[j] = (unsigned char)r;
            }
        }
    }
}

__global__ __launch_bounds__(256) void k_scan_a(const int* __restrict__ deg,
                                                int* __restrict__ offs,
                                                int* __restrict__ bsum, int n16) {
    __shared__ int sdata[256];
    int tid = threadIdx.x;
    int base = blockIdx.x * SCAN_EPB;
    int i0 = base + tid * 8;
    int vals[8];
    int s = 0;
#pragma unroll
    for (int j = 0; j < 8; ++j) {
        int i = i0 + j;
        int d = (i < n16) ? deg[i] : 0;
        vals[j] = s;
        s += d;
    }
    sdata[tid] = s;
    __syncthreads();
    for (int off = 1; off < 256; off <<= 1) {
        int y = (tid >= off) ? sdata[tid - off] : 0;
        __syncthreads();
        sdata[tid] += y;
        __syncthreads();
    }
    int texcl = sdata[tid] - s;
#pragma unroll
    for (int j = 0; j < 8; ++j) {
        int i = i0 + j;
        if (i < n16) offs[i] = texcl + vals[j];
    }
    if (tid == 255) bsum[blockIdx.x] = sdata[255];
}

__global__ __launch_bounds__(1024) void k_scan_b(int* bsum, int nb) {
    __shared__ int sd[1024];
    int tid = threadIdx.x;
    int v = (tid < nb) ? bsum[tid] : 0;
    sd[tid] = v;
    __syncthreads();
    for (int off = 1; off < 1024; off <<= 1) {
        int y = (tid >= off) ? sd[tid - off] : 0;
        __syncthreads();
        sd[tid] += y;
        __syncthreads();
    }
    if (tid < nb) bsum[tid] = sd[tid] - v;   // exclusive
}

__global__ __launch_bounds__(256) void k_finalize(int* __restrict__ offs,
                                                  const int* __restrict__ bsum,
                                                  const int* __restrict__ deg,
                                                  float* __restrict__ dinv, int n) {
    int i = blockIdx.x * blockDim.x + threadIdx.x;
    int n16 = n * SHPAD;
    if (i >= n16) return;
    offs[i] += bsum[i / SCAN_EPB];
    if ((i & 15) == 0) {
        const int4* dp = (const int4*)&deg[i];
        int4 a = dp[0], b = dp[1], c = dp[2], d = dp[3];
        int tot = a.x + a.y + a.z + a.w + b.x + b.y + b.z + b.w +
                  c.x + c.y + c.z + c.w + d.x + d.y + d.z + d.w;
        dinv[i >> 4] = rsqrtf((float)(tot + 1));
    }
}

__global__ __launch_bounds__(256) void k_fill2(const int* __restrict__ src,
                                               const int* __restrict__ dst,
                                               const unsigned char* __restrict__ rank,
                                               const int* __restrict__ offs,
                                               int* __restrict__ csr,
                                               int E, int nbuckets) {
    __shared__ int sdst[CHUNK];
    __shared__ int ssrc[CHUNK];
    __shared__ unsigned char srank[CHUNK];
    int base = blockIdx.x * CHUNK;
    int cnt = min(CHUNK, E - base);
    for (int j = threadIdx.x; j < cnt; j += 256) {
        sdst[j] = __builtin_nontemporal_load(&dst[base + j]);
        ssrc[j] = __builtin_nontemporal_load(&src[base + j]);
    }
    for (int j = threadIdx.x * 4; j < cnt; j += 1024) {
        *(unsigned*)&srank[j] = __builtin_nontemporal_load((const unsigned*)&rank[base + j]);
    }
    __syncthreads();
    for (int p = 0; p < nbuckets; ++p) {
        for (int j = threadIdx.x; j < cnt; j += 256) {
            int d = sdst[j];
            if ((d >> BSHIFT) == p) {
                int s = ssrc[j];
                csr[offs[(d << 4) | (s >> SHSHIFT)] + srank[j]] = s;
            }
        }
        __syncthreads();
    }
}

// ---------------- dense GEMM: H = X @ W  (M x 128 @ 128 x 128, fp32 in, bf16 out)

#define GBM 64
#define GBK 32
__global__ __launch_bounds__(256) void k_gemm128(const float* __restrict__ X,
                                                 const float* __restrict__ W,
                                                 unsigned short* __restrict__ H, int nrows) {
    __shared__ float xs[GBM][GBK + 1];
    __shared__ float ws[GBK][D];
    int tid = threadIdx.x;
    int tc = tid & 31;
    int tr = tid >> 5;
    int m0 = blockIdx.x * GBM;
    float acc[8][4] = {};
    for (int kk = 0; kk < D; kk += GBK) {
        for (int i = tid; i < GBM * GBK; i += 256) {
            int r = i >> 5, c = i & 31;
            int gr = m0 + r;
            xs[r][c] = (gr < nrows) ? X[(size_t)gr * D + kk + c] : 0.f;
        }
        for (int i = tid; i < GBK * D; i += 256) {
            int r = i >> 7, c = i & 127;
            ws[r][c] = W[(size_t)(kk + r) * D + c];
        }
        __syncthreads();
#pragma unroll 4
        for (int k = 0; k < GBK; ++k) {
            float a[8];
#pragma unroll
            for (int ri = 0; ri < 8; ++ri) a[ri] = xs[tr * 8 + ri][k];
            float4 bv = *(const float4*)&ws[k][tc * 4];
            float b[4] = {bv.x, bv.y, bv.z, bv.w};
#pragma unroll
            for (int ri = 0; ri < 8; ++ri)
#pragma unroll
                for (int ci = 0; ci < 4; ++ci)
                    acc[ri][ci] += a[ri] * b[ci];
        }
        __syncthreads();
    }
#pragma unroll
    for (int ri = 0; ri < 8; ++ri) {
        int gr = m0 + tr * 8 + ri;
        if (gr < nrows) {
            ushort4 v;
            v.x = f2bf(acc[ri][0]); v.y = f2bf(acc[ri][1]);
            v.z = f2bf(acc[ri][2]); v.w = f2bf(acc[ri][3]);
            *(ushort4*)&H[(size_t)gr * D + tc * 4] = v;
        }
    }
}

// ---------------- layer-1 aggregation: H1[v] = relu(sum norm*H[src] + self + b1), bf16 out

__global__ __launch_bounds__(256) void k_agg(const unsigned short* __restrict__ H,
                                             const int* __restrict__ offs,
                                             const int* __restrict__ csr,
                                             const float* __restrict__ dinv,
                                             const float* __restrict__ bias,
                                             unsigned short* __restrict__ Out,
                                             int n, int E) {
    int wid = threadIdx.x >> 6;
    int lane = threadIdx.x & 63;
    int v = blockIdx.x * 4 + wid;
    if (v >= n) return;
    float dv = dinv[v];
    unsigned us = *(const unsigned*)(H + (size_t)v * D + lane * 2);
    float2 hs = bf2_to_f2(us);
    float dv2 = dv * dv;
    float2 acc = make_float2(hs.x * dv2, hs.y * dv2);
    int e = offs[v << 4];
    int eE = (v == n - 1) ? E : offs[(v + 1) << 4];
    for (; e + 3 < eE; e += 4) {
        int s0 = csr[e], s1 = csr[e + 1], s2 = csr[e + 2], s3 = csr[e + 3];
        unsigned u0 = *(const unsigned*)(H + (size_t)s0 * D + lane * 2);
        unsigned u1 = *(const unsigned*)(H + (size_t)s1 * D + lane * 2);
        unsigned u2 = *(const unsigned*)(H + (size_t)s2 * D + lane * 2);
        unsigned u3 = *(const unsigned*)(H + (size_t)s3 * D + lane * 2);
        float w0 = dinv[s0] * dv, w1 = dinv[s1] * dv;
        float w2 = dinv[s2] * dv, w3 = dinv[s3] * dv;
        float2 h0 = bf2_to_f2(u0), h1 = bf2_to_f2(u1);
        float2 h2 = bf2_to_f2(u2), h3 = bf2_to_f2(u3);
        acc.x += h0.x * w0; acc.y += h0.y * w0;
        acc.x += h1.x * w1; acc.y += h1.y * w1;
        acc.x += h2.x * w2; acc.y += h2.y * w2;
        acc.x += h3.x * w3; acc.y += h3.y * w3;
    }
    for (; e < eE; ++e) {
        int s0 = csr[e];
        float w0 = dinv[s0] * dv;
        unsigned u0 = *(const unsigned*)(H + (size_t)s0 * D + lane * 2);
        float2 h0 = bf2_to_f2(u0);
        acc.x += h0.x * w0; acc.y += h0.y * w0;
    }
    float2 b = ((const float2*)bias)[lane];
    acc.x = fmaxf(acc.x + b.x, 0.f);
    acc.y = fmaxf(acc.y + b.y, 0.f);
    unsigned pack = (unsigned)f2bf(acc.x) | ((unsigned)f2bf(acc.y) << 16);
    *(unsigned*)(Out + (size_t)v * D + lane * 2) = pack;
}

// ---------------- fused layer-2 agg + mean-pool (graph-level accumulators in LDS)
// t[g] += norm_e * H1[src_e] for edges with batch[dst_e]==g, plus dv^2*H1[v] self terms.

__global__ __launch_bounds__(1024) void k_agg_pool(const unsigned short* __restrict__ H1,
                                                   const int* __restrict__ src,
                                                   const int* __restrict__ dst,
                                                   const float* __restrict__ dinv,
                                                   const int* __restrict__ batch,
                                                   float* __restrict__ part,
                                                   int* __restrict__ cnt,
                                                   int n, int E) {
    __shared__ float t[NGRAPH * D];
    __shared__ int scnt[NGRAPH];
    int tid = threadIdx.x;
    for (int i = tid; i < NGRAPH * D; i += 1024) t[i] = 0.f;
    if (tid < NGRAPH) scnt[tid] = 0;
    __syncthreads();
    int wid = tid >> 6, lane = tid & 63;
    int gw = blockIdx.x * 16 + wid;
    int l2 = lane * 2;
    // edge phase: 64-edge chunks strided over all waves
    int nch = (E + 63) >> 6;
    for (int c = gw; c < nch; c += APWAVES) {
        int e = c * 64 + lane;
        int s = 0, g = 0; float w = 0.f;
        if (e < E) {
            s = src[e];
            int d = dst[e];
            w = dinv[s] * dinv[d];
            g = batch[d];
        }
        int cn = min(64, E - c * 64);
        if (cn == 64) {
#pragma unroll 8
            for (int j = 0; j < 64; ++j) {
                int sj = __shfl(s, j, 64);
                int gj = __shfl(g, j, 64);
                float wj = __shfl(w, j, 64);
                unsigned u = *(const unsigned*)(H1 + (size_t)sj * D + l2);
                float2 h = bf2_to_f2(u);
                atomicAdd(&t[gj * D + l2],     h.x * wj);
                atomicAdd(&t[gj * D + l2 + 1], h.y * wj);
            }
        } else {
            for (int j = 0; j < cn; ++j) {
                int sj = __shfl(s, j, 64);
                int gj = __shfl(g, j, 64);
                float wj = __shfl(w, j, 64);
                unsigned u = *(const unsigned*)(H1 + (size_t)sj * D + l2);
                float2 h = bf2_to_f2(u);
                atomicAdd(&t[gj * D + l2],     h.x * wj);
                atomicAdd(&t[gj * D + l2 + 1], h.y * wj);
            }
        }
    }
    // self-loop + count phase: 64-node chunks
    int nnch = (n + 63) >> 6;
    for (int c = gw; c < nnch; c += APWAVES) {
        int v = c * 64 + lane;
        int g = 0; float w = 0.f;
        if (v < n) {
            float dv = dinv[v];
            w = dv * dv;
            g = batch[v];
            atomicAdd(&scnt[g], 1);
        }
        int cn = min(64, n - c * 64);
        for (int j = 0; j < cn; ++j) {
            int vj = c * 64 + j;
            int gj = __shfl(g, j, 64);
            float wj = __shfl(w, j, 64);
            unsigned u = *(const unsigned*)(H1 + (size_t)vj * D + l2);
            float2 h = bf2_to_f2(u);
            atomicAdd(&t[gj * D + l2],     h.x * wj);
            atomicAdd(&t[gj * D + l2 + 1], h.y * wj);
        }
    }
    __syncthreads();
    float* pb = part + (size_t)blockIdx.x * (NGRAPH * D);
    for (int i = tid; i < NGRAPH * D; i += 1024) pb[i] = t[i];
    if (tid < NGRAPH && scnt[tid]) atomicAdd(&cnt[tid], scnt[tid]);
}

// reduce part[APBLK][8192] -> tsum[8192]  (coalesced)
__global__ __launch_bounds__(256) void k_reduce(const float* __restrict__ part,
                                                float* __restrict__ tsum) {
    int t = blockIdx.x * 256 + threadIdx.x;   // 8192 threads
    float s = 0.f;
    for (int b = 0; b < APBLK; ++b) s += part[(size_t)b * (NGRAPH * D) + t];
    tsum[t] = s;
}

// Weff = W2 @ Wc (128x2), beff = b2 @ Wc + bc (2)
__global__ void k_foldW(const float* __restrict__ W2, const float* __restrict__ Wc,
                        const float* __restrict__ b2, const float* __restrict__ bc,
                        float* __restrict__ Weff, float* __restrict__ beff) {
    int t = threadIdx.x;          // 256 threads: i = t>>1, c = t&1
    int i = t >> 1, c = t & 1;
    float acc = 0.f;
    for (int k = 0; k < D; ++k) acc += W2[i * D + k] * Wc[k * 2 + c];
    Weff[i * 2 + c] = acc;
    if (i == 0) {
        float s = 0.f;
        for (int k = 0; k < D; ++k) s += b2[k] * Wc[k * 2 + c];
        beff[c] = s + bc[c];
    }
}

__global__ void k_classify(const float* __restrict__ tsum, const int* __restrict__ cnt,
                           const float* __restrict__ Weff, const float* __restrict__ beff,
                           const float* __restrict__ bc, float* __restrict__ out) {
    int t = threadIdx.x;          // 128 threads: g = t>>1, c = t&1
    if (t >= NGRAPH * 2) return;
    int g = t >> 1, c = t & 1;
    int cg = cnt[g];
    if (cg == 0) { out[t] = bc[c]; return; }
    float inv = 1.0f / (float)cg;
    float acc = 0.f;
    for (int k = 0; k < D; ++k) acc += tsum[g * D + k] * Weff[k * 2 + c];
    out[t] = acc * inv + beff[c];
}

// ---------------- launch ----------------

extern "C" void kernel_launch(void* const* d_in, const int* in_sizes, int n_in,
                              void* d_out, int out_size, void* d_ws, size_t ws_size,
                              hipStream_t stream) {
    const float* x    = (const float*)d_in[0];
    const int*   ei   = (const int*)d_in[1];
    const int*   batch= (const int*)d_in[2];
    const float* W1   = (const float*)d_in[3];
    const float* b1   = (const float*)d_in[4];
    const float* W2   = (const float*)d_in[5];
    const float* b2   = (const float*)d_in[6];
    const float* Wc   = (const float*)d_in[7];
    const float* bc   = (const float*)d_in[8];

    const int n = in_sizes[0] / D;       // 100000
    const int E = in_sizes[1] / 2;       // 3200000
    const int* src = ei;
    const int* dst = ei + E;
    const int n16 = n * SHPAD;

    char* ws = (char*)d_ws;
    size_t off = 0;
    auto carve = [&](size_t bytes) -> char* {
        char* p = ws + off;
        off = (off + bytes + 255) & ~(size_t)255;
        return p;
    };
    unsigned short* bufBF = (unsigned short*)carve((size_t)n * D * 2);  // xW1 (bf16)
    unsigned short* bufH1 = (unsigned short*)carve((size_t)n * D * 2);  // h1 (bf16)
    int*   csr    = (int*)  carve((size_t)E * 4);
    unsigned char* rank = (unsigned char*)carve((size_t)E);
    int*   deg    = (int*)  carve((size_t)n16 * 4);
    int*   offs   = (int*)  carve((size_t)n16 * 4);
    float* dinv   = (float*)carve((size_t)n * 4);
    int*   bsum   = (int*)  carve(1024 * 4);
    float* part   = (float*)carve((size_t)APBLK * NGRAPH * D * 4);
    float* tsum   = (float*)carve((size_t)NGRAPH * D * 4);
    float* Weff   = (float*)carve(D * 2 * 4);
    float* beff   = (float*)carve(2 * 4);
    int*   cnt    = (int*)  carve(NGRAPH * 4);

    const int nb = (n16 + SCAN_EPB - 1) / SCAN_EPB;   // 782 <= 1024
    const int nbuckets = (n >> BSHIFT) + 1;           // 13 for n=100000

    hipMemsetAsync(deg, 0, (size_t)n16 * 4, stream);
    hipMemsetAsync(cnt, 0, NGRAPH * 4, stream);

    k_count<<<(E / 4 + 255) / 256, 256, 0, stream>>>(src, dst, deg, rank, E);
    k_scan_a<<<nb, 256, 0, stream>>>(deg, offs, bsum, n16);
    k_scan_b<<<1, 1024, 0, stream>>>(bsum, nb);
    k_finalize<<<(n16 + 255) / 256, 256, 0, stream>>>(offs, bsum, deg, dinv, n);
    k_fill2<<<(E + CHUNK - 1) / CHUNK, 256, 0, stream>>>(src, dst, rank, offs, csr, E, nbuckets);
    k_foldW<<<1, 256, 0, stream>>>(W2, Wc, b2, bc, Weff, beff);

    // layer 1: h1 = relu(agg(x @ W1) + b1)   (bf16 out)
    k_gemm128<<<(n + GBM - 1) / GBM, 256, 0, stream>>>(x, W1, bufBF, n);
    k_agg<<<(n + 3) / 4, 256, 0, stream>>>(bufBF, offs, csr, dinv, b1, bufH1, n, E);

    // fused layer-2 agg + pool -> per-graph sums
    k_agg_pool<<<APBLK, 1024, 0, stream>>>(bufH1, src, dst, dinv, batch, part, cnt, n, E);
    k_reduce<<<NGRAPH * D / 256, 256, 0, stream>>>(part, tsum);
    k_classify<<<1, 128, 0, stream>>>(tsum, cnt, Weff, beff, bc, (float*)d_out);
}

// Round 6
// 781.096 us; speedup vs baseline: 3.6816x; 3.6816x over previous
//
#include <hip/hip_runtime.h>
#include <hip/hip_bf16.h>

#define D 128
#define NGRAPH 64
#define SCAN_EPB 2048   // elements per scan block (256 thr * 8)
#define CHUNK 4096      // edges staged in LDS per block in k_fill2
#define BSHIFT 13       // dst-bucket = dst >> 13 (8192 nodes/bucket, ~1MB csr window)
#define SHSHIFT 13      // src-shard = src >> 13 (13 shards of 8192 nodes, 2MB bf16 each)
#define SHPAD 16        // counters per node (13 shards padded to 16)
#define APBLK 512       // blocks in k_agg_pool2 (4 waves each -> 2048 strips)
#define APWAVES (APBLK * 4)

__device__ __forceinline__ unsigned short f2bf(float f) {
    union { float f; unsigned int i; } u; u.f = f;
    unsigned int r = u.i + 0x7fffu + ((u.i >> 16) & 1u);   // round-to-nearest-even
    return (unsigned short)(r >> 16);
}
__device__ __forceinline__ float2 bf2_to_f2(unsigned int u) {
    union { unsigned int i; float f; } a, b;
    a.i = u << 16;            // low ushort  = element 0
    b.i = u & 0xffff0000u;    // high ushort = element 1
    return make_float2(a.f, b.f);
}

// ---------------- CSR build ----------------

__global__ __launch_bounds__(256) void k_count(const int* __restrict__ src,
                                               const int* __restrict__ dst,
                                               int* __restrict__ deg,
                                               unsigned char* __restrict__ rank, int E) {
    int i = (blockIdx.x * blockDim.x + threadIdx.x) * 4;
    int stride = gridDim.x * blockDim.x * 4;
    for (; i < E; i += stride) {
        if (i + 3 < E) {
            int4 d4 = *(const int4*)&dst[i];
            int4 s4 = *(const int4*)&src[i];
            int r0 = atomicAdd(&deg[(d4.x << 4) | (s4.x >> SHSHIFT)], 1);
            int r1 = atomicAdd(&deg[(d4.y << 4) | (s4.y >> SHSHIFT)], 1);
            int r2 = atomicAdd(&deg[(d4.z << 4) | (s4.z >> SHSHIFT)], 1);
            int r3 = atomicAdd(&deg[(d4.w << 4) | (s4.w >> SHSHIFT)], 1);
            unsigned pack = (unsigned)(r0 & 0xff) | ((unsigned)(r1 & 0xff) << 8) |
                            ((unsigned)(r2 & 0xff) << 16) | ((unsigned)(r3 & 0xff) << 24);
            __builtin_nontemporal_store(pack, (unsigned*)&rank[i]);
        } else {
            for (int j = i; j < E; ++j) {
                int d = dst[j], s = src[j];
                int r = atomicAdd(&deg[(d << 4) | (s >> SHSHIFT)], 1);
                rank[j] = (unsigned char)r;
            }
        }
    }
}

__global__ __launch_bounds__(256) void k_scan_a(const int* __restrict__ deg,
                                                int* __restrict__ offs,
                                                int* __restrict__ bsum, int n16) {
    __shared__ int sdata[256];
    int tid = threadIdx.x;
    int base = blockIdx.x * SCAN_EPB;
    int i0 = base + tid * 8;
    int vals[8];
    int s = 0;
#pragma unroll
    for (int j = 0; j < 8; ++j) {
        int i = i0 + j;
        int d = (i < n16) ? deg[i] : 0;
        vals[j] = s;
        s += d;
    }
    sdata[tid] = s;
    __syncthreads();
    for (int off = 1; off < 256; off <<= 1) {
        int y = (tid >= off) ? sdata[tid - off] : 0;
        __syncthreads();
        sdata[tid] += y;
        __syncthreads();
    }
    int texcl = sdata[tid] - s;
#pragma unroll
    for (int j = 0; j < 8; ++j) {
        int i = i0 + j;
        if (i < n16) offs[i] = texcl + vals[j];
    }
    if (tid == 255) bsum[blockIdx.x] = sdata[255];
}

__global__ __launch_bounds__(1024) void k_scan_b(int* bsum, int nb) {
    __shared__ int sd[1024];
    int tid = threadIdx.x;
    int v = (tid < nb) ? bsum[tid] : 0;
    sd[tid] = v;
    __syncthreads();
    for (int off = 1; off < 1024; off <<= 1) {
        int y = (tid >= off) ? sd[tid - off] : 0;
        __syncthreads();
        sd[tid] += y;
        __syncthreads();
    }
    if (tid < nb) bsum[tid] = sd[tid] - v;   // exclusive
}

__global__ __launch_bounds__(256) void k_finalize(int* __restrict__ offs,
                                                  const int* __restrict__ bsum,
                                                  const int* __restrict__ deg,
                                                  float* __restrict__ dinv, int n) {
    int i = blockIdx.x * blockDim.x + threadIdx.x;
    int n16 = n * SHPAD;
    if (i >= n16) return;
    offs[i] += bsum[i / SCAN_EPB];
    if ((i & 15) == 0) {
        const int4* dp = (const int4*)&deg[i];
        int4 a = dp[0], b = dp[1], c = dp[2], d = dp[3];
        int tot = a.x + a.y + a.z + a.w + b.x + b.y + b.z + b.w +
                  c.x + c.y + c.z + c.w + d.x + d.y + d.z + d.w;
        dinv[i >> 4] = rsqrtf((float)(tot + 1));
    }
}

__global__ __launch_bounds__(256) void k_fill2(const int* __restrict__ src,
                                               const int* __restrict__ dst,
                                               const unsigned char* __restrict__ rank,
                                               const int* __restrict__ offs,
                                               int* __restrict__ csr,
                                               int E, int nbuckets) {
    __shared__ int sdst[CHUNK];
    __shared__ int ssrc[CHUNK];
    __shared__ unsigned char srank[CHUNK];
    int base = blockIdx.x * CHUNK;
    int cnt = min(CHUNK, E - base);
    for (int j = threadIdx.x; j < cnt; j += 256) {
        sdst[j] = __builtin_nontemporal_load(&dst[base + j]);
        ssrc[j] = __builtin_nontemporal_load(&src[base + j]);
    }
    for (int j = threadIdx.x * 4; j < cnt; j += 1024) {
        *(unsigned*)&srank[j] = __builtin_nontemporal_load((const unsigned*)&rank[base + j]);
    }
    __syncthreads();
    for (int p = 0; p < nbuckets; ++p) {
        for (int j = threadIdx.x; j < cnt; j += 256) {
            int d = sdst[j];
            if ((d >> BSHIFT) == p) {
                int s = ssrc[j];
                csr[offs[(d << 4) | (s >> SHSHIFT)] + srank[j]] = s;
            }
        }
        __syncthreads();
    }
}

// ---------------- dense GEMM: H = X @ W  (M x 128 @ 128 x 128, fp32 in, bf16 out)

#define GBM 64
#define GBK 32
__global__ __launch_bounds__(256) void k_gemm128(const float* __restrict__ X,
                                                 const float* __restrict__ W,
                                                 unsigned short* __restrict__ H, int nrows) {
    __shared__ float xs[GBM][GBK + 1];
    __shared__ float ws[GBK][D];
    int tid = threadIdx.x;
    int tc = tid & 31;
    int tr = tid >> 5;
    int m0 = blockIdx.x * GBM;
    float acc[8][4] = {};
    for (int kk = 0; kk < D; kk += GBK) {
        for (int i = tid; i < GBM * GBK; i += 256) {
            int r = i >> 5, c = i & 31;
            int gr = m0 + r;
            xs[r][c] = (gr < nrows) ? X[(size_t)gr * D + kk + c] : 0.f;
        }
        for (int i = tid; i < GBK * D; i += 256) {
            int r = i >> 7, c = i & 127;
            ws[r][c] = W[(size_t)(kk + r) * D + c];
        }
        __syncthreads();
#pragma unroll 4
        for (int k = 0; k < GBK; ++k) {
            float a[8];
#pragma unroll
            for (int ri = 0; ri < 8; ++ri) a[ri] = xs[tr * 8 + ri][k];
            float4 bv = *(const float4*)&ws[k][tc * 4];
            float b[4] = {bv.x, bv.y, bv.z, bv.w};
#pragma unroll
            for (int ri = 0; ri < 8; ++ri)
#pragma unroll
                for (int ci = 0; ci < 4; ++ci)
                    acc[ri][ci] += a[ri] * b[ci];
        }
        __syncthreads();
    }
#pragma unroll
    for (int ri = 0; ri < 8; ++ri) {
        int gr = m0 + tr * 8 + ri;
        if (gr < nrows) {
            ushort4 v;
            v.x = f2bf(acc[ri][0]); v.y = f2bf(acc[ri][1]);
            v.z = f2bf(acc[ri][2]); v.w = f2bf(acc[ri][3]);
            *(ushort4*)&H[(size_t)gr * D + tc * 4] = v;
        }
    }
}

// ---------------- layer-1 aggregation: H1[v] = relu(sum norm*H[src] + self + b1), bf16 out

__global__ __launch_bounds__(256) void k_agg(const unsigned short* __restrict__ H,
                                             const int* __restrict__ offs,
                                             const int* __restrict__ csr,
                                             const float* __restrict__ dinv,
                                             const float* __restrict__ bias,
                                             unsigned short* __restrict__ Out,
                                             int n, int E) {
    int wid = threadIdx.x >> 6;
    int lane = threadIdx.x & 63;
    int v = blockIdx.x * 4 + wid;
    if (v >= n) return;
    float dv = dinv[v];
    unsigned us = *(const unsigned*)(H + (size_t)v * D + lane * 2);
    float2 hs = bf2_to_f2(us);
    float dv2 = dv * dv;
    float2 acc = make_float2(hs.x * dv2, hs.y * dv2);
    int e = offs[v << 4];
    int eE = (v == n - 1) ? E : offs[(v + 1) << 4];
    for (; e + 3 < eE; e += 4) {
        int s0 = csr[e], s1 = csr[e + 1], s2 = csr[e + 2], s3 = csr[e + 3];
        unsigned u0 = *(const unsigned*)(H + (size_t)s0 * D + lane * 2);
        unsigned u1 = *(const unsigned*)(H + (size_t)s1 * D + lane * 2);
        unsigned u2 = *(const unsigned*)(H + (size_t)s2 * D + lane * 2);
        unsigned u3 = *(const unsigned*)(H + (size_t)s3 * D + lane * 2);
        float w0 = dinv[s0] * dv, w1 = dinv[s1] * dv;
        float w2 = dinv[s2] * dv, w3 = dinv[s3] * dv;
        float2 h0 = bf2_to_f2(u0), h1 = bf2_to_f2(u1);
        float2 h2 = bf2_to_f2(u2), h3 = bf2_to_f2(u3);
        acc.x += h0.x * w0; acc.y += h0.y * w0;
        acc.x += h1.x * w1; acc.y += h1.y * w1;
        acc.x += h2.x * w2; acc.y += h2.y * w2;
        acc.x += h3.x * w3; acc.y += h3.y * w3;
    }
    for (; e < eE; ++e) {
        int s0 = csr[e];
        float w0 = dinv[s0] * dv;
        unsigned u0 = *(const unsigned*)(H + (size_t)s0 * D + lane * 2);
        float2 h0 = bf2_to_f2(u0);
        acc.x += h0.x * w0; acc.y += h0.y * w0;
    }
    float2 b = ((const float2*)bias)[lane];
    acc.x = fmaxf(acc.x + b.x, 0.f);
    acc.y = fmaxf(acc.y + b.y, 0.f);
    unsigned pack = (unsigned)f2bf(acc.x) | ((unsigned)f2bf(acc.y) << 16);
    *(unsigned*)(Out + (size_t)v * D + lane * 2) = pack;
}

// ---------------- fused layer-2 agg + mean-pool --------------------------
// Each wave owns a contiguous node strip (batch sorted). Per node: gather the
// GCN aggregation into registers (same structure as k_agg); accumulate into a
// running per-graph register sum; flush to tsum[g][] via global atomicAdd only
// on graph change / strip end. Node counts ride along (lane 0).

__global__ __launch_bounds__(256) void k_agg_pool2(const unsigned short* __restrict__ H1,
                                                   const int* __restrict__ offs,
                                                   const int* __restrict__ csr,
                                                   const float* __restrict__ dinv,
                                                   const int* __restrict__ batch,
                                                   float* __restrict__ tsum,
                                                   int* __restrict__ cnt,
                                                   int n, int E) {
    int wid = threadIdx.x >> 6;
    int lane = threadIdx.x & 63;
    int w = blockIdx.x * 4 + wid;
    int nper = (n + APWAVES - 1) / APWAVES;
    int v0 = w * nper;
    if (v0 >= n) return;
    int vend = min(v0 + nper, n);
    int l2 = lane * 2;

    float2 racc = make_float2(0.f, 0.f);
    int gcur = batch[v0];
    int count = 0;

    for (int v = v0; v < vend; ++v) {
        int g = batch[v];
        if (g != gcur) {
            atomicAdd(&tsum[gcur * D + l2],     racc.x);
            atomicAdd(&tsum[gcur * D + l2 + 1], racc.y);
            if (lane == 0) atomicAdd(&cnt[gcur], count);
            racc.x = racc.y = 0.f; count = 0; gcur = g;
        }
        float dv = dinv[v];
        unsigned us = *(const unsigned*)(H1 + (size_t)v * D + l2);
        float2 hs = bf2_to_f2(us);
        float dv2 = dv * dv;
        float2 acc = make_float2(hs.x * dv2, hs.y * dv2);
        int e = offs[v << 4];
        int eE = (v == n - 1) ? E : offs[(v + 1) << 4];
        for (; e + 3 < eE; e += 4) {
            int s0 = csr[e], s1 = csr[e + 1], s2 = csr[e + 2], s3 = csr[e + 3];
            unsigned u0 = *(const unsigned*)(H1 + (size_t)s0 * D + l2);
            unsigned u1 = *(const unsigned*)(H1 + (size_t)s1 * D + l2);
            unsigned u2 = *(const unsigned*)(H1 + (size_t)s2 * D + l2);
            unsigned u3 = *(const unsigned*)(H1 + (size_t)s3 * D + l2);
            float w0 = dinv[s0] * dv, w1 = dinv[s1] * dv;
            float w2 = dinv[s2] * dv, w3 = dinv[s3] * dv;
            float2 h0 = bf2_to_f2(u0), h1 = bf2_to_f2(u1);
            float2 h2 = bf2_to_f2(u2), h3 = bf2_to_f2(u3);
            acc.x += h0.x * w0; acc.y += h0.y * w0;
            acc.x += h1.x * w1; acc.y += h1.y * w1;
            acc.x += h2.x * w2; acc.y += h2.y * w2;
            acc.x += h3.x * w3; acc.y += h3.y * w3;
        }
        for (; e < eE; ++e) {
            int s0 = csr[e];
            float w0 = dinv[s0] * dv;
            unsigned u0 = *(const unsigned*)(H1 + (size_t)s0 * D + l2);
            float2 h0 = bf2_to_f2(u0);
            acc.x += h0.x * w0; acc.y += h0.y * w0;
        }
        racc.x += acc.x; racc.y += acc.y;
        ++count;
    }
    atomicAdd(&tsum[gcur * D + l2],     racc.x);
    atomicAdd(&tsum[gcur * D + l2 + 1], racc.y);
    if (lane == 0) atomicAdd(&cnt[gcur], count);
}

// Weff = W2 @ Wc (128x2), beff = b2 @ Wc + bc (2)
__global__ void k_foldW(const float* __restrict__ W2, const float* __restrict__ Wc,
                        const float* __restrict__ b2, const float* __restrict__ bc,
                        float* __restrict__ Weff, float* __restrict__ beff) {
    int t = threadIdx.x;          // 256 threads: i = t>>1, c = t&1
    int i = t >> 1, c = t & 1;
    float acc = 0.f;
    for (int k = 0; k < D; ++k) acc += W2[i * D + k] * Wc[k * 2 + c];
    Weff[i * 2 + c] = acc;
    if (i == 0) {
        float s = 0.f;
        for (int k = 0; k < D; ++k) s += b2[k] * Wc[k * 2 + c];
        beff[c] = s + bc[c];
    }
}

__global__ void k_classify(const float* __restrict__ tsum, const int* __restrict__ cnt,
                           const float* __restrict__ Weff, const float* __restrict__ beff,
                           const float* __restrict__ bc, float* __restrict__ out) {
    int t = threadIdx.x;          // 128 threads: g = t>>1, c = t&1
    if (t >= NGRAPH * 2) return;
    int g = t >> 1, c = t & 1;
    int cg = cnt[g];
    if (cg == 0) { out[t] = bc[c]; return; }
    float inv = 1.0f / (float)cg;
    float acc = 0.f;
    for (int k = 0; k < D; ++k) acc += tsum[g * D + k] * Weff[k * 2 + c];
    out[t] = acc * inv + beff[c];
}

// ---------------- launch ----------------

extern "C" void kernel_launch(void* const* d_in, const int* in_sizes, int n_in,
                              void* d_out, int out_size, void* d_ws, size_t ws_size,
                              hipStream_t stream) {
    const float* x    = (const float*)d_in[0];
    const int*   ei   = (const int*)d_in[1];
    const int*   batch= (const int*)d_in[2];
    const float* W1   = (const float*)d_in[3];
    const float* b1   = (const float*)d_in[4];
    const float* W2   = (const float*)d_in[5];
    const float* b2   = (const float*)d_in[6];
    const float* Wc   = (const float*)d_in[7];
    const float* bc   = (const float*)d_in[8];

    const int n = in_sizes[0] / D;       // 100000
    const int E = in_sizes[1] / 2;       // 3200000
    const int* src = ei;
    const int* dst = ei + E;
    const int n16 = n * SHPAD;

    char* ws = (char*)d_ws;
    size_t off = 0;
    auto carve = [&](size_t bytes) -> char* {
        char* p = ws + off;
        off = (off + bytes + 255) & ~(size_t)255;
        return p;
    };
    unsigned short* bufBF = (unsigned short*)carve((size_t)n * D * 2);  // xW1 (bf16)
    unsigned short* bufH1 = (unsigned short*)carve((size_t)n * D * 2);  // h1 (bf16)
    int*   csr    = (int*)  carve((size_t)E * 4);
    unsigned char* rank = (unsigned char*)carve((size_t)E);
    int*   deg    = (int*)  carve((size_t)n16 * 4);
    int*   offs   = (int*)  carve((size_t)n16 * 4);
    float* dinv   = (float*)carve((size_t)n * 4);
    int*   bsum   = (int*)  carve(1024 * 4);
    float* tsum   = (float*)carve((size_t)NGRAPH * D * 4);
    float* Weff   = (float*)carve(D * 2 * 4);
    float* beff   = (float*)carve(2 * 4);
    int*   cnt    = (int*)  carve(NGRAPH * 4);

    const int nb = (n16 + SCAN_EPB - 1) / SCAN_EPB;   // 782 <= 1024
    const int nbuckets = (n >> BSHIFT) + 1;           // 13 for n=100000

    hipMemsetAsync(deg, 0, (size_t)n16 * 4, stream);
    hipMemsetAsync(tsum, 0, (size_t)NGRAPH * D * 4, stream);
    hipMemsetAsync(cnt, 0, NGRAPH * 4, stream);

    k_count<<<(E / 4 + 255) / 256, 256, 0, stream>>>(src, dst, deg, rank, E);
    k_scan_a<<<nb, 256, 0, stream>>>(deg, offs, bsum, n16);
    k_scan_b<<<1, 1024, 0, stream>>>(bsum, nb);
    k_finalize<<<(n16 + 255) / 256, 256, 0, stream>>>(offs, bsum, deg, dinv, n);
    k_fill2<<<(E + CHUNK - 1) / CHUNK, 256, 0, stream>>>(src, dst, rank, offs, csr, E, nbuckets);
    k_foldW<<<1, 256, 0, stream>>>(W2, Wc, b2, bc, Weff, beff);

    // layer 1: h1 = relu(agg(x @ W1) + b1)   (bf16 out)
    k_gemm128<<<(n + GBM - 1) / GBM, 256, 0, stream>>>(x, W1, bufBF, n);
    k_agg<<<(n + 3) / 4, 256, 0, stream>>>(bufBF, offs, csr, dinv, b1, bufH1, n, E);

    // fused layer-2 agg + mean-pool -> per-graph sums
    k_agg_pool2<<<APBLK, 256, 0, stream>>>(bufH1, offs, csr, dinv, batch, tsum, cnt, n, E);
    k_classify<<<1, 128, 0, stream>>>(tsum, cnt, Weff, beff, bc, (float*)d_out);
}

// Round 7
// 587.766 us; speedup vs baseline: 4.8926x; 1.3289x over previous
//
#include <hip/hip_runtime.h>
#include <hip/hip_bf16.h>

#define D 128
#define NGRAPH 64
#define SCAN_EPB 2048   // elements per scan block (256 thr * 8)
#define CHUNK 4096      // edges staged in LDS per block in k_fill2
#define BSHIFT 13       // dst-bucket = dst >> 13 (8192 nodes/bucket, ~1MB csr window)
#define SHSHIFT 13      // src-shard = src >> 13 (13 shards of 8192 nodes, 2MB bf16 each)
#define SHPAD 16        // counters per node (13 shards padded to 16)
#define APBLK 2048      // blocks in k_agg_pool2 (4 waves each -> 8192 strips, full occupancy)
#define APWAVES (APBLK * 4)

__device__ __forceinline__ unsigned short f2bf(float f) {
    union { float f; unsigned int i; } u; u.f = f;
    unsigned int r = u.i + 0x7fffu + ((u.i >> 16) & 1u);   // round-to-nearest-even
    return (unsigned short)(r >> 16);
}
__device__ __forceinline__ float2 bf2_to_f2(unsigned int u) {
    union { unsigned int i; float f; } a, b;
    a.i = u << 16;            // low ushort  = element 0
    b.i = u & 0xffff0000u;    // high ushort = element 1
    return make_float2(a.f, b.f);
}

// ---------------- CSR build ----------------

__global__ __launch_bounds__(256) void k_count(const int* __restrict__ src,
                                               const int* __restrict__ dst,
                                               int* __restrict__ deg,
                                               unsigned char* __restrict__ rank, int E) {
    int i = (blockIdx.x * blockDim.x + threadIdx.x) * 4;
    int stride = gridDim.x * blockDim.x * 4;
    for (; i < E; i += stride) {
        if (i + 3 < E) {
            int4 d4 = *(const int4*)&dst[i];
            int4 s4 = *(const int4*)&src[i];
            int r0 = atomicAdd(&deg[(d4.x << 4) | (s4.x >> SHSHIFT)], 1);
            int r1 = atomicAdd(&deg[(d4.y << 4) | (s4.y >> SHSHIFT)], 1);
            int r2 = atomicAdd(&deg[(d4.z << 4) | (s4.z >> SHSHIFT)], 1);
            int r3 = atomicAdd(&deg[(d4.w << 4) | (s4.w >> SHSHIFT)], 1);
            unsigned pack = (unsigned)(r0 & 0xff) | ((unsigned)(r1 & 0xff) << 8) |
                            ((unsigned)(r2 & 0xff) << 16) | ((unsigned)(r3 & 0xff) << 24);
            __builtin_nontemporal_store(pack, (unsigned*)&rank[i]);
        } else {
            for (int j = i; j < E; ++j) {
                int d = dst[j], s = src[j];
                int r = atomicAdd(&deg[(d << 4) | (s >> SHSHIFT)], 1);
                rank[j] = (unsigned char)r;
            }
        }
    }
}

__global__ __launch_bounds__(256) void k_scan_a(const int* __restrict__ deg,
                                                int* __restrict__ offs,
                                                int* __restrict__ bsum, int n16) {
    __shared__ int sdata[256];
    int tid = threadIdx.x;
    int base = blockIdx.x * SCAN_EPB;
    int i0 = base + tid * 8;
    int vals[8];
    int s = 0;
#pragma unroll
    for (int j = 0; j < 8; ++j) {
        int i = i0 + j;
        int d = (i < n16) ? deg[i] : 0;
        vals[j] = s;
        s += d;
    }
    sdata[tid] = s;
    __syncthreads();
    for (int off = 1; off < 256; off <<= 1) {
        int y = (tid >= off) ? sdata[tid - off] : 0;
        __syncthreads();
        sdata[tid] += y;
        __syncthreads();
    }
    int texcl = sdata[tid] - s;
#pragma unroll
    for (int j = 0; j < 8; ++j) {
        int i = i0 + j;
        if (i < n16) offs[i] = texcl + vals[j];
    }
    if (tid == 255) bsum[blockIdx.x] = sdata[255];
}

__global__ __launch_bounds__(1024) void k_scan_b(int* bsum, int nb) {
    __shared__ int sd[1024];
    int tid = threadIdx.x;
    int v = (tid < nb) ? bsum[tid] : 0;
    sd[tid] = v;
    __syncthreads();
    for (int off = 1; off < 1024; off <<= 1) {
        int y = (tid >= off) ? sd[tid - off] : 0;
        __syncthreads();
        sd[tid] += y;
        __syncthreads();
    }
    if (tid < nb) bsum[tid] = sd[tid] - v;   // exclusive
}

__global__ __launch_bounds__(256) void k_finalize(int* __restrict__ offs,
                                                  const int* __restrict__ bsum,
                                                  const int* __restrict__ deg,
                                                  float* __restrict__ dinv, int n) {
    int i = blockIdx.x * blockDim.x + threadIdx.x;
    int n16 = n * SHPAD;
    if (i >= n16) return;
    offs[i] += bsum[i / SCAN_EPB];
    if ((i & 15) == 0) {
        const int4* dp = (const int4*)&deg[i];
        int4 a = dp[0], b = dp[1], c = dp[2], d = dp[3];
        int tot = a.x + a.y + a.z + a.w + b.x + b.y + b.z + b.w +
                  c.x + c.y + c.z + c.w + d.x + d.y + d.z + d.w;
        dinv[i >> 4] = rsqrtf((float)(tot + 1));
    }
}

__global__ __launch_bounds__(256) void k_fill2(const int* __restrict__ src,
                                               const int* __restrict__ dst,
                                               const unsigned char* __restrict__ rank,
                                               const int* __restrict__ offs,
                                               int* __restrict__ csr,
                                               int E, int nbuckets) {
    __shared__ int sdst[CHUNK];
    __shared__ int ssrc[CHUNK];
    __shared__ unsigned char srank[CHUNK];
    int base = blockIdx.x * CHUNK;
    int cnt = min(CHUNK, E - base);
    for (int j = threadIdx.x; j < cnt; j += 256) {
        sdst[j] = __builtin_nontemporal_load(&dst[base + j]);
        ssrc[j] = __builtin_nontemporal_load(&src[base + j]);
    }
    for (int j = threadIdx.x * 4; j < cnt; j += 1024) {
        *(unsigned*)&srank[j] = __builtin_nontemporal_load((const unsigned*)&rank[base + j]);
    }
    __syncthreads();
    for (int p = 0; p < nbuckets; ++p) {
        for (int j = threadIdx.x; j < cnt; j += 256) {
            int d = sdst[j];
            if ((d >> BSHIFT) == p) {
                int s = ssrc[j];
                csr[offs[(d << 4) | (s >> SHSHIFT)] + srank[j]] = s;
            }
        }
        __syncthreads();
    }
}

// ---------------- dense GEMM: H = X @ W  (M x 128 @ 128 x 128, fp32 in, bf16 out)

#define GBM 64
#define GBK 32
__global__ __launch_bounds__(256) void k_gemm128(const float* __restrict__ X,
                                                 const float* __restrict__ W,
                                                 unsigned short* __restrict__ H, int nrows) {
    __shared__ float xs[GBM][GBK + 1];
    __shared__ float ws[GBK][D];
    int tid = threadIdx.x;
    int tc = tid & 31;
    int tr = tid >> 5;
    int m0 = blockIdx.x * GBM;
    float acc[8][4] = {};
    for (int kk = 0; kk < D; kk += GBK) {
        for (int i = tid; i < GBM * GBK; i += 256) {
            int r = i >> 5, c = i & 31;
            int gr = m0 + r;
            xs[r][c] = (gr < nrows) ? X[(size_t)gr * D + kk + c] : 0.f;
        }
        for (int i = tid; i < GBK * D; i += 256) {
            int r = i >> 7, c = i & 127;
            ws[r][c] = W[(size_t)(kk + r) * D + c];
        }
        __syncthreads();
#pragma unroll 4
        for (int k = 0; k < GBK; ++k) {
            float a[8];
#pragma unroll
            for (int ri = 0; ri < 8; ++ri) a[ri] = xs[tr * 8 + ri][k];
            float4 bv = *(const float4*)&ws[k][tc * 4];
            float b[4] = {bv.x, bv.y, bv.z, bv.w};
#pragma unroll
            for (int ri = 0; ri < 8; ++ri)
#pragma unroll
                for (int ci = 0; ci < 4; ++ci)
                    acc[ri][ci] += a[ri] * b[ci];
        }
        __syncthreads();
    }
#pragma unroll
    for (int ri = 0; ri < 8; ++ri) {
        int gr = m0 + tr * 8 + ri;
        if (gr < nrows) {
            ushort4 v;
            v.x = f2bf(acc[ri][0]); v.y = f2bf(acc[ri][1]);
            v.z = f2bf(acc[ri][2]); v.w = f2bf(acc[ri][3]);
            *(ushort4*)&H[(size_t)gr * D + tc * 4] = v;
        }
    }
}

// ---------------- layer-1 aggregation: H1[v] = relu(sum norm*H[src] + self + b1), bf16 out

__global__ __launch_bounds__(256) void k_agg(const unsigned short* __restrict__ H,
                                             const int* __restrict__ offs,
                                             const int* __restrict__ csr,
                                             const float* __restrict__ dinv,
                                             const float* __restrict__ bias,
                                             unsigned short* __restrict__ Out,
                                             int n, int E) {
    int wid = threadIdx.x >> 6;
    int lane = threadIdx.x & 63;
    int v = blockIdx.x * 4 + wid;
    if (v >= n) return;
    float dv = dinv[v];
    unsigned us = *(const unsigned*)(H + (size_t)v * D + lane * 2);
    float2 hs = bf2_to_f2(us);
    float dv2 = dv * dv;
    float2 acc = make_float2(hs.x * dv2, hs.y * dv2);
    int e = offs[v << 4];
    int eE = (v == n - 1) ? E : offs[(v + 1) << 4];
    for (; e + 3 < eE; e += 4) {
        int s0 = csr[e], s1 = csr[e + 1], s2 = csr[e + 2], s3 = csr[e + 3];
        unsigned u0 = *(const unsigned*)(H + (size_t)s0 * D + lane * 2);
        unsigned u1 = *(const unsigned*)(H + (size_t)s1 * D + lane * 2);
        unsigned u2 = *(const unsigned*)(H + (size_t)s2 * D + lane * 2);
        unsigned u3 = *(const unsigned*)(H + (size_t)s3 * D + lane * 2);
        float w0 = dinv[s0] * dv, w1 = dinv[s1] * dv;
        float w2 = dinv[s2] * dv, w3 = dinv[s3] * dv;
        float2 h0 = bf2_to_f2(u0), h1 = bf2_to_f2(u1);
        float2 h2 = bf2_to_f2(u2), h3 = bf2_to_f2(u3);
        acc.x += h0.x * w0; acc.y += h0.y * w0;
        acc.x += h1.x * w1; acc.y += h1.y * w1;
        acc.x += h2.x * w2; acc.y += h2.y * w2;
        acc.x += h3.x * w3; acc.y += h3.y * w3;
    }
    for (; e < eE; ++e) {
        int s0 = csr[e];
        float w0 = dinv[s0] * dv;
        unsigned u0 = *(const unsigned*)(H + (size_t)s0 * D + lane * 2);
        float2 h0 = bf2_to_f2(u0);
        acc.x += h0.x * w0; acc.y += h0.y * w0;
    }
    float2 b = ((const float2*)bias)[lane];
    acc.x = fmaxf(acc.x + b.x, 0.f);
    acc.y = fmaxf(acc.y + b.y, 0.f);
    unsigned pack = (unsigned)f2bf(acc.x) | ((unsigned)f2bf(acc.y) << 16);
    *(unsigned*)(Out + (size_t)v * D + lane * 2) = pack;
}

// ---------------- fused layer-2 agg + mean-pool --------------------------
// Each wave owns a contiguous node strip (batch sorted). Per node: gather the
// GCN aggregation into registers; accumulate into a running per-graph register
// sum; flush to tsum[g][] via global atomicAdd only on graph change / strip end.

__global__ __launch_bounds__(256) void k_agg_pool2(const unsigned short* __restrict__ H1,
                                                   const int* __restrict__ offs,
                                                   const int* __restrict__ csr,
                                                   const float* __restrict__ dinv,
                                                   const int* __restrict__ batch,
                                                   float* __restrict__ tsum,
                                                   int* __restrict__ cnt,
                                                   int n, int E) {
    int wid = threadIdx.x >> 6;
    int lane = threadIdx.x & 63;
    int w = blockIdx.x * 4 + wid;
    int nper = (n + APWAVES - 1) / APWAVES;
    int v0 = w * nper;
    if (v0 >= n) return;
    int vend = min(v0 + nper, n);
    int l2 = lane * 2;

    float2 racc = make_float2(0.f, 0.f);
    int gcur = batch[v0];
    int count = 0;

    for (int v = v0; v < vend; ++v) {
        int g = batch[v];
        if (g != gcur) {
            atomicAdd(&tsum[gcur * D + l2],     racc.x);
            atomicAdd(&tsum[gcur * D + l2 + 1], racc.y);
            if (lane == 0) atomicAdd(&cnt[gcur], count);
            racc.x = racc.y = 0.f; count = 0; gcur = g;
        }
        float dv = dinv[v];
        unsigned us = *(const unsigned*)(H1 + (size_t)v * D + l2);
        float2 hs = bf2_to_f2(us);
        float dv2 = dv * dv;
        float2 acc = make_float2(hs.x * dv2, hs.y * dv2);
        int e = offs[v << 4];
        int eE = (v == n - 1) ? E : offs[(v + 1) << 4];
        for (; e + 3 < eE; e += 4) {
            int s0 = csr[e], s1 = csr[e + 1], s2 = csr[e + 2], s3 = csr[e + 3];
            unsigned u0 = *(const unsigned*)(H1 + (size_t)s0 * D + l2);
            unsigned u1 = *(const unsigned*)(H1 + (size_t)s1 * D + l2);
            unsigned u2 = *(const unsigned*)(H1 + (size_t)s2 * D + l2);
            unsigned u3 = *(const unsigned*)(H1 + (size_t)s3 * D + l2);
            float w0 = dinv[s0] * dv, w1 = dinv[s1] * dv;
            float w2 = dinv[s2] * dv, w3 = dinv[s3] * dv;
            float2 h0 = bf2_to_f2(u0), h1 = bf2_to_f2(u1);
            float2 h2 = bf2_to_f2(u2), h3 = bf2_to_f2(u3);
            acc.x += h0.x * w0; acc.y += h0.y * w0;
            acc.x += h1.x * w1; acc.y += h1.y * w1;
            acc.x += h2.x * w2; acc.y += h2.y * w2;
            acc.x += h3.x * w3; acc.y += h3.y * w3;
        }
        for (; e < eE; ++e) {
            int s0 = csr[e];
            float w0 = dinv[s0] * dv;
            unsigned u0 = *(const unsigned*)(H1 + (size_t)s0 * D + l2);
            float2 h0 = bf2_to_f2(u0);
            acc.x += h0.x * w0; acc.y += h0.y * w0;
        }
        racc.x += acc.x; racc.y += acc.y;
        ++count;
    }
    atomicAdd(&tsum[gcur * D + l2],     racc.x);
    atomicAdd(&tsum[gcur * D + l2 + 1], racc.y);
    if (lane == 0) atomicAdd(&cnt[gcur], count);
}

// Weff = W2 @ Wc (128x2), beff = b2 @ Wc + bc (2)
__global__ void k_foldW(const float* __restrict__ W2, const float* __restrict__ Wc,
                        const float* __restrict__ b2, const float* __restrict__ bc,
                        float* __restrict__ Weff, float* __restrict__ beff) {
    int t = threadIdx.x;          // 256 threads: i = t>>1, c = t&1
    int i = t >> 1, c = t & 1;
    float acc = 0.f;
    for (int k = 0; k < D; ++k) acc += W2[i * D + k] * Wc[k * 2 + c];
    Weff[i * 2 + c] = acc;
    if (i == 0) {
        float s = 0.f;
        for (int k = 0; k < D; ++k) s += b2[k] * Wc[k * 2 + c];
        beff[c] = s + bc[c];
    }
}

__global__ void k_classify(const float* __restrict__ tsum, const int* __restrict__ cnt,
                           const float* __restrict__ Weff, const float* __restrict__ beff,
                           const float* __restrict__ bc, float* __restrict__ out) {
    int t = threadIdx.x;          // 128 threads: g = t>>1, c = t&1
    if (t >= NGRAPH * 2) return;
    int g = t >> 1, c = t & 1;
    int cg = cnt[g];
    if (cg == 0) { out[t] = bc[c]; return; }
    float inv = 1.0f / (float)cg;
    float acc = 0.f;
    for (int k = 0; k < D; ++k) acc += tsum[g * D + k] * Weff[k * 2 + c];
    out[t] = acc * inv + beff[c];
}

// ---------------- launch ----------------

extern "C" void kernel_launch(void* const* d_in, const int* in_sizes, int n_in,
                              void* d_out, int out_size, void* d_ws, size_t ws_size,
                              hipStream_t stream) {
    const float* x    = (const float*)d_in[0];
    const int*   ei   = (const int*)d_in[1];
    const int*   batch= (const int*)d_in[2];
    const float* W1   = (const float*)d_in[3];
    const float* b1   = (const float*)d_in[4];
    const float* W2   = (const float*)d_in[5];
    const float* b2   = (const float*)d_in[6];
    const float* Wc   = (const float*)d_in[7];
    const float* bc   = (const float*)d_in[8];

    const int n = in_sizes[0] / D;       // 100000
    const int E = in_sizes[1] / 2;       // 3200000
    const int* src = ei;
    const int* dst = ei + E;
    const int n16 = n * SHPAD;

    char* ws = (char*)d_ws;
    size_t off = 0;
    auto carve = [&](size_t bytes) -> char* {
        char* p = ws + off;
        off = (off + bytes + 255) & ~(size_t)255;
        return p;
    };
    unsigned short* bufBF = (unsigned short*)carve((size_t)n * D * 2);  // xW1 (bf16)
    unsigned short* bufH1 = (unsigned short*)carve((size_t)n * D * 2);  // h1 (bf16)
    int*   csr    = (int*)  carve((size_t)E * 4);
    unsigned char* rank = (unsigned char*)carve((size_t)E);
    int*   deg    = (int*)  carve((size_t)n16 * 4);
    int*   offs   = (int*)  carve((size_t)n16 * 4);
    float* dinv   = (float*)carve((size_t)n * 4);
    int*   bsum   = (int*)  carve(1024 * 4);
    float* tsum   = (float*)carve((size_t)NGRAPH * D * 4);
    float* Weff   = (float*)carve(D * 2 * 4);
    float* beff   = (float*)carve(2 * 4);
    int*   cnt    = (int*)  carve(NGRAPH * 4);

    const int nb = (n16 + SCAN_EPB - 1) / SCAN_EPB;   // 782 <= 1024
    const int nbuckets = (n >> BSHIFT) + 1;           // 13 for n=100000

    hipMemsetAsync(deg, 0, (size_t)n16 * 4, stream);
    hipMemsetAsync(tsum, 0, (size_t)NGRAPH * D * 4, stream);
    hipMemsetAsync(cnt, 0, NGRAPH * 4, stream);

    k_count<<<(E / 4 + 255) / 256, 256, 0, stream>>>(src, dst, deg, rank, E);
    k_scan_a<<<nb, 256, 0, stream>>>(deg, offs, bsum, n16);
    k_scan_b<<<1, 1024, 0, stream>>>(bsum, nb);
    k_finalize<<<(n16 + 255) / 256, 256, 0, stream>>>(offs, bsum, deg, dinv, n);
    k_fill2<<<(E + CHUNK - 1) / CHUNK, 256, 0, stream>>>(src, dst, rank, offs, csr, E, nbuckets);
    k_foldW<<<1, 256, 0, stream>>>(W2, Wc, b2, bc, Weff, beff);

    // layer 1: h1 = relu(agg(x @ W1) + b1)   (bf16 out)
    k_gemm128<<<(n + GBM - 1) / GBM, 256, 0, stream>>>(x, W1, bufBF, n);
    k_agg<<<(n + 3) / 4, 256, 0, stream>>>(bufBF, offs, csr, dinv, b1, bufH1, n, E);

    // fused layer-2 agg + mean-pool -> per-graph sums
    k_agg_pool2<<<APBLK, 256, 0, stream>>>(bufH1, offs, csr, dinv, batch, tsum, cnt, n, E);
    k_classify<<<1, 128, 0, stream>>>(tsum, cnt, Weff, beff, bc, (float*)d_out);
}

// Round 8
// 510.268 us; speedup vs baseline: 5.6357x; 1.1519x over previous
//
#include <hip/hip_runtime.h>
#include <hip/hip_bf16.h>

#define D 128
#define NGRAPH 64
#define SCAN_EPB 2048   // elements per scan block (256 thr * 8)
#define CHUNK 4096      // edges staged in LDS per block in k_fill2
#define BSHIFT 13       // dst-bucket = dst >> 13 (8192 nodes/bucket, ~1MB csr window)
#define SHSHIFT 13      // src-shard = src >> 13
#define SHPAD 16        // counters per node (13 shards padded to 16)
#define POOLBLK 1024    // blocks in k_pool_edges

__device__ __forceinline__ unsigned short f2bf(float f) {
    union { float f; unsigned int i; } u; u.f = f;
    unsigned int r = u.i + 0x7fffu + ((u.i >> 16) & 1u);   // round-to-nearest-even
    return (unsigned short)(r >> 16);
}
__device__ __forceinline__ float2 bf2_to_f2(unsigned int u) {
    union { unsigned int i; float f; } a, b;
    a.i = u << 16;            // low ushort  = element 0
    b.i = u & 0xffff0000u;    // high ushort = element 1
    return make_float2(a.f, b.f);
}

// ---------------- CSR build ----------------

__global__ __launch_bounds__(256) void k_count(const int* __restrict__ src,
                                               const int* __restrict__ dst,
                                               int* __restrict__ deg,
                                               unsigned char* __restrict__ rank, int E) {
    int i = (blockIdx.x * blockDim.x + threadIdx.x) * 4;
    int stride = gridDim.x * blockDim.x * 4;
    for (; i < E; i += stride) {
        if (i + 3 < E) {
            int4 d4 = *(const int4*)&dst[i];
            int4 s4 = *(const int4*)&src[i];
            int r0 = atomicAdd(&deg[(d4.x << 4) | (s4.x >> SHSHIFT)], 1);
            int r1 = atomicAdd(&deg[(d4.y << 4) | (s4.y >> SHSHIFT)], 1);
            int r2 = atomicAdd(&deg[(d4.z << 4) | (s4.z >> SHSHIFT)], 1);
            int r3 = atomicAdd(&deg[(d4.w << 4) | (s4.w >> SHSHIFT)], 1);
            unsigned pack = (unsigned)(r0 & 0xff) | ((unsigned)(r1 & 0xff) << 8) |
                            ((unsigned)(r2 & 0xff) << 16) | ((unsigned)(r3 & 0xff) << 24);
            __builtin_nontemporal_store(pack, (unsigned*)&rank[i]);
        } else {
            for (int j = i; j < E; ++j) {
                int d = dst[j], s = src[j];
                int r = atomicAdd(&deg[(d << 4) | (s >> SHSHIFT)], 1);
                rank[j] = (unsigned char)r;
            }
        }
    }
}

__global__ __launch_bounds__(256) void k_scan_a(const int* __restrict__ deg,
                                                int* __restrict__ offs,
                                                int* __restrict__ bsum, int n16) {
    __shared__ int sdata[256];
    int tid = threadIdx.x;
    int base = blockIdx.x * SCAN_EPB;
    int i0 = base + tid * 8;
    int vals[8];
    int s = 0;
#pragma unroll
    for (int j = 0; j < 8; ++j) {
        int i = i0 + j;
        int d = (i < n16) ? deg[i] : 0;
        vals[j] = s;
        s += d;
    }
    sdata[tid] = s;
    __syncthreads();
    for (int off = 1; off < 256; off <<= 1) {
        int y = (tid >= off) ? sdata[tid - off] : 0;
        __syncthreads();
        sdata[tid] += y;
        __syncthreads();
    }
    int texcl = sdata[tid] - s;
#pragma unroll
    for (int j = 0; j < 8; ++j) {
        int i = i0 + j;
        if (i < n16) offs[i] = texcl + vals[j];
    }
    if (tid == 255) bsum[blockIdx.x] = sdata[255];
}

__global__ __launch_bounds__(1024) void k_scan_b(int* bsum, int nb) {
    __shared__ int sd[1024];
    int tid = threadIdx.x;
    int v = (tid < nb) ? bsum[tid] : 0;
    sd[tid] = v;
    __syncthreads();
    for (int off = 1; off < 1024; off <<= 1) {
        int y = (tid >= off) ? sd[tid - off] : 0;
        __syncthreads();
        sd[tid] += y;
        __syncthreads();
    }
    if (tid < nb) bsum[tid] = sd[tid] - v;   // exclusive
}

__global__ __launch_bounds__(256) void k_finalize(int* __restrict__ offs,
                                                  const int* __restrict__ bsum,
                                                  const int* __restrict__ deg,
                                                  float* __restrict__ dinv, int n) {
    int i = blockIdx.x * blockDim.x + threadIdx.x;
    int n16 = n * SHPAD;
    if (i >= n16) return;
    offs[i] += bsum[i / SCAN_EPB];
    if ((i & 15) == 0) {
        const int4* dp = (const int4*)&deg[i];
        int4 a = dp[0], b = dp[1], c = dp[2], d = dp[3];
        int tot = a.x + a.y + a.z + a.w + b.x + b.y + b.z + b.w +
                  c.x + c.y + c.z + c.w + d.x + d.y + d.z + d.w;
        dinv[i >> 4] = rsqrtf((float)(tot + 1));
    }
}

__global__ __launch_bounds__(256) void k_fill2(const int* __restrict__ src,
                                               const int* __restrict__ dst,
                                               const unsigned char* __restrict__ rank,
                                               const int* __restrict__ offs,
                                               int* __restrict__ csr,
                                               int E, int nbuckets) {
    __shared__ int sdst[CHUNK];
    __shared__ int ssrc[CHUNK];
    __shared__ unsigned char srank[CHUNK];
    int base = blockIdx.x * CHUNK;
    int cnt = min(CHUNK, E - base);
    for (int j = threadIdx.x; j < cnt; j += 256) {
        sdst[j] = __builtin_nontemporal_load(&dst[base + j]);
        ssrc[j] = __builtin_nontemporal_load(&src[base + j]);
    }
    for (int j = threadIdx.x * 4; j < cnt; j += 1024) {
        *(unsigned*)&srank[j] = __builtin_nontemporal_load((const unsigned*)&rank[base + j]);
    }
    __syncthreads();
    for (int p = 0; p < nbuckets; ++p) {
        for (int j = threadIdx.x; j < cnt; j += 256) {
            int d = sdst[j];
            if ((d >> BSHIFT) == p) {
                int s = ssrc[j];
                csr[offs[(d << 4) | (s >> SHSHIFT)] + srank[j]] = s;
            }
        }
        __syncthreads();
    }
}

// ---------------- dense GEMM: H = X @ W  (M x 128 @ 128 x 128, fp32 in, bf16 out)

#define GBM 64
#define GBK 32
__global__ __launch_bounds__(256) void k_gemm128(const float* __restrict__ X,
                                                 const float* __restrict__ W,
                                                 unsigned short* __restrict__ H, int nrows) {
    __shared__ float xs[GBM][GBK + 1];
    __shared__ float ws[GBK][D];
    int tid = threadIdx.x;
    int tc = tid & 31;
    int tr = tid >> 5;
    int m0 = blockIdx.x * GBM;
    float acc[8][4] = {};
    for (int kk = 0; kk < D; kk += GBK) {
        for (int i = tid; i < GBM * GBK; i += 256) {
            int r = i >> 5, c = i & 31;
            int gr = m0 + r;
            xs[r][c] = (gr < nrows) ? X[(size_t)gr * D + kk + c] : 0.f;
        }
        for (int i = tid; i < GBK * D; i += 256) {
            int r = i >> 7, c = i & 127;
            ws[r][c] = W[(size_t)(kk + r) * D + c];
        }
        __syncthreads();
#pragma unroll 4
        for (int k = 0; k < GBK; ++k) {
            float a[8];
#pragma unroll
            for (int ri = 0; ri < 8; ++ri) a[ri] = xs[tr * 8 + ri][k];
            float4 bv = *(const float4*)&ws[k][tc * 4];
            float b[4] = {bv.x, bv.y, bv.z, bv.w};
#pragma unroll
            for (int ri = 0; ri < 8; ++ri)
#pragma unroll
                for (int ci = 0; ci < 4; ++ci)
                    acc[ri][ci] += a[ri] * b[ci];
        }
        __syncthreads();
    }
#pragma unroll
    for (int ri = 0; ri < 8; ++ri) {
        int gr = m0 + tr * 8 + ri;
        if (gr < nrows) {
            ushort4 v;
            v.x = f2bf(acc[ri][0]); v.y = f2bf(acc[ri][1]);
            v.z = f2bf(acc[ri][2]); v.w = f2bf(acc[ri][3]);
            *(ushort4*)&H[(size_t)gr * D + tc * 4] = v;
        }
    }
}

// ---------------- layer-1 agg + relu + 2-dim projection ------------------
// z[v] = relu(agg1(xW1)[v] + b1) @ Weff   (fp32, 8B per node)

__global__ __launch_bounds__(256) void k_agg_proj(const unsigned short* __restrict__ H,
                                                  const int* __restrict__ offs,
                                                  const int* __restrict__ csr,
                                                  const float* __restrict__ dinv,
                                                  const float* __restrict__ bias,
                                                  const float* __restrict__ Weff,
                                                  float2* __restrict__ z,
                                                  int n, int E) {
    int wid = threadIdx.x >> 6;
    int lane = threadIdx.x & 63;
    int v = blockIdx.x * 4 + wid;
    if (v >= n) return;
    float dv = dinv[v];
    int l2 = lane * 2;
    unsigned us = *(const unsigned*)(H + (size_t)v * D + l2);
    float2 hs = bf2_to_f2(us);
    float dv2 = dv * dv;
    float2 acc = make_float2(hs.x * dv2, hs.y * dv2);
    int e = offs[v << 4];
    int eE = (v == n - 1) ? E : offs[(v + 1) << 4];
    for (; e + 3 < eE; e += 4) {
        int s0 = csr[e], s1 = csr[e + 1], s2 = csr[e + 2], s3 = csr[e + 3];
        unsigned u0 = *(const unsigned*)(H + (size_t)s0 * D + l2);
        unsigned u1 = *(const unsigned*)(H + (size_t)s1 * D + l2);
        unsigned u2 = *(const unsigned*)(H + (size_t)s2 * D + l2);
        unsigned u3 = *(const unsigned*)(H + (size_t)s3 * D + l2);
        float w0 = dinv[s0] * dv, w1 = dinv[s1] * dv;
        float w2 = dinv[s2] * dv, w3 = dinv[s3] * dv;
        float2 h0 = bf2_to_f2(u0), h1 = bf2_to_f2(u1);
        float2 h2 = bf2_to_f2(u2), h3 = bf2_to_f2(u3);
        acc.x += h0.x * w0; acc.y += h0.y * w0;
        acc.x += h1.x * w1; acc.y += h1.y * w1;
        acc.x += h2.x * w2; acc.y += h2.y * w2;
        acc.x += h3.x * w3; acc.y += h3.y * w3;
    }
    for (; e < eE; ++e) {
        int s0 = csr[e];
        float w0 = dinv[s0] * dv;
        unsigned u0 = *(const unsigned*)(H + (size_t)s0 * D + l2);
        float2 h0 = bf2_to_f2(u0);
        acc.x += h0.x * w0; acc.y += h0.y * w0;
    }
    float2 b = ((const float2*)bias)[lane];
    acc.x = fmaxf(acc.x + b.x, 0.f);
    acc.y = fmaxf(acc.y + b.y, 0.f);
    // project: lane term = acc.x*Weff[l2][c] + acc.y*Weff[l2+1][c]
    float4 wv = *(const float4*)&Weff[l2 * 2];   // {W[l2][0],W[l2][1],W[l2+1][0],W[l2+1][1]}
    float z0 = acc.x * wv.x + acc.y * wv.z;
    float z1 = acc.x * wv.y + acc.y * wv.w;
#pragma unroll
    for (int off = 32; off >= 1; off >>= 1) {
        z0 += __shfl_xor(z0, off, 64);
        z1 += __shfl_xor(z1, off, 64);
    }
    if (lane == 0) z[v] = make_float2(z0, z1);
}

// ---------------- fused layer-2 agg + mean-pool on projected z -----------
// part[b][g][2] += norm_e * z[src_e] (edges) + dv^2 * z[v] (self); counts too.

__global__ __launch_bounds__(256) void k_pool_edges(const float2* __restrict__ z,
                                                    const int* __restrict__ src,
                                                    const int* __restrict__ dst,
                                                    const float* __restrict__ dinv,
                                                    const int* __restrict__ batch,
                                                    float* __restrict__ part,
                                                    int* __restrict__ pcnt,
                                                    int n, int E) {
    __shared__ float t[NGRAPH * 2];
    __shared__ int scnt[NGRAPH];
    int tid = threadIdx.x;
    if (tid < NGRAPH * 2) t[tid] = 0.f;
    if (tid < NGRAPH) scnt[tid] = 0;
    __syncthreads();

    // edge phase: 4 edges per thread per iter, coalesced int4 loads
    int i = (blockIdx.x * 256 + tid) * 4;
    int stride = POOLBLK * 256 * 4;
    for (; i < E; i += stride) {
        if (i + 3 < E) {
            int4 s4 = *(const int4*)&src[i];
            int4 d4 = *(const int4*)&dst[i];
            float w0 = dinv[s4.x] * dinv[d4.x];
            float w1 = dinv[s4.y] * dinv[d4.y];
            float w2 = dinv[s4.z] * dinv[d4.z];
            float w3 = dinv[s4.w] * dinv[d4.w];
            float2 z0 = z[s4.x], z1 = z[s4.y], z2 = z[s4.z], z3 = z[s4.w];
            int g0 = batch[d4.x], g1 = batch[d4.y], g2 = batch[d4.z], g3 = batch[d4.w];
            atomicAdd(&t[g0 * 2],     w0 * z0.x);
            atomicAdd(&t[g0 * 2 + 1], w0 * z0.y);
            atomicAdd(&t[g1 * 2],     w1 * z1.x);
            atomicAdd(&t[g1 * 2 + 1], w1 * z1.y);
            atomicAdd(&t[g2 * 2],     w2 * z2.x);
            atomicAdd(&t[g2 * 2 + 1], w2 * z2.y);
            atomicAdd(&t[g3 * 2],     w3 * z3.x);
            atomicAdd(&t[g3 * 2 + 1], w3 * z3.y);
        } else {
            for (int j = i; j < E; ++j) {
                int s = src[j], d = dst[j];
                float w = dinv[s] * dinv[d];
                float2 zv = z[s];
                int g = batch[d];
                atomicAdd(&t[g * 2],     w * zv.x);
                atomicAdd(&t[g * 2 + 1], w * zv.y);
            }
        }
    }
    // self-loop + count phase
    for (int v = blockIdx.x * 256 + tid; v < n; v += POOLBLK * 256) {
        float dv = dinv[v];
        float2 zv = z[v];
        int g = batch[v];
        float w = dv * dv;
        atomicAdd(&t[g * 2],     w * zv.x);
        atomicAdd(&t[g * 2 + 1], w * zv.y);
        atomicAdd(&scnt[g], 1);
    }
    __syncthreads();
    if (tid < NGRAPH * 2) part[blockIdx.x * (NGRAPH * 2) + tid] = t[tid];
    if (tid < NGRAPH) pcnt[blockIdx.x * NGRAPH + tid] = scnt[tid];
}

// Weff = W2 @ Wc (128x2), beff = b2 @ Wc + bc (2)
__global__ void k_foldW(const float* __restrict__ W2, const float* __restrict__ Wc,
                        const float* __restrict__ b2, const float* __restrict__ bc,
                        float* __restrict__ Weff, float* __restrict__ beff) {
    int t = threadIdx.x;          // 256 threads: i = t>>1, c = t&1
    int i = t >> 1, c = t & 1;
    float acc = 0.f;
    for (int k = 0; k < D; ++k) acc += W2[i * D + k] * Wc[k * 2 + c];
    Weff[i * 2 + c] = acc;
    if (i == 0) {
        float s = 0.f;
        for (int k = 0; k < D; ++k) s += b2[k] * Wc[k * 2 + c];
        beff[c] = s + bc[c];
    }
}

// reduce partials + classify in one tiny kernel
__global__ __launch_bounds__(256) void k_finalpool(const float* __restrict__ part,
                                                   const int* __restrict__ pcnt,
                                                   const float* __restrict__ beff,
                                                   const float* __restrict__ bc,
                                                   float* __restrict__ out) {
    __shared__ float tz[NGRAPH * 2];
    __shared__ int tc[NGRAPH];
    int tid = threadIdx.x;
    if (tid < NGRAPH * 2) {
        float s0 = 0.f, s1 = 0.f, s2 = 0.f, s3 = 0.f;
        int b = 0;
        for (; b + 3 < POOLBLK; b += 4) {
            s0 += part[(b + 0) * (NGRAPH * 2) + tid];
            s1 += part[(b + 1) * (NGRAPH * 2) + tid];
            s2 += part[(b + 2) * (NGRAPH * 2) + tid];
            s3 += part[(b + 3) * (NGRAPH * 2) + tid];
        }
        for (; b < POOLBLK; ++b) s0 += part[b * (NGRAPH * 2) + tid];
        tz[tid] = (s0 + s1) + (s2 + s3);
    } else if (tid < NGRAPH * 2 + NGRAPH) {
        int g = tid - NGRAPH * 2;
        int s0 = 0, s1 = 0, s2 = 0, s3 = 0;
        int b = 0;
        for (; b + 3 < POOLBLK; b += 4) {
            s0 += pcnt[(b + 0) * NGRAPH + g];
            s1 += pcnt[(b + 1) * NGRAPH + g];
            s2 += pcnt[(b + 2) * NGRAPH + g];
            s3 += pcnt[(b + 3) * NGRAPH + g];
        }
        for (; b < POOLBLK; ++b) s0 += pcnt[b * NGRAPH + g];
        tc[g] = (s0 + s1) + (s2 + s3);
    }
    __syncthreads();
    if (tid < NGRAPH * 2) {
        int g = tid >> 1, c = tid & 1;
        int cg = tc[g];
        out[tid] = cg ? (tz[tid] / (float)cg + beff[c]) : bc[c];
    }
}

// ---------------- launch ----------------

extern "C" void kernel_launch(void* const* d_in, const int* in_sizes, int n_in,
                              void* d_out, int out_size, void* d_ws, size_t ws_size,
                              hipStream_t stream) {
    const float* x    = (const float*)d_in[0];
    const int*   ei   = (const int*)d_in[1];
    const int*   batch= (const int*)d_in[2];
    const float* W1   = (const float*)d_in[3];
    const float* b1   = (const float*)d_in[4];
    const float* W2   = (const float*)d_in[5];
    const float* b2   = (const float*)d_in[6];
    const float* Wc   = (const float*)d_in[7];
    const float* bc   = (const float*)d_in[8];

    const int n = in_sizes[0] / D;       // 100000
    const int E = in_sizes[1] / 2;       // 3200000
    const int* src = ei;
    const int* dst = ei + E;
    const int n16 = n * SHPAD;

    char* ws = (char*)d_ws;
    size_t off = 0;
    auto carve = [&](size_t bytes) -> char* {
        char* p = ws + off;
        off = (off + bytes + 255) & ~(size_t)255;
        return p;
    };
    unsigned short* bufBF = (unsigned short*)carve((size_t)n * D * 2);  // xW1 (bf16)
    float2* z     = (float2*)carve((size_t)n * 8);                      // projected h1
    int*   csr    = (int*)  carve((size_t)E * 4);
    unsigned char* rank = (unsigned char*)carve((size_t)E);
    int*   deg    = (int*)  carve((size_t)n16 * 4);
    int*   offs   = (int*)  carve((size_t)n16 * 4);
    float* dinv   = (float*)carve((size_t)n * 4);
    int*   bsum   = (int*)  carve(1024 * 4);
    float* part   = (float*)carve((size_t)POOLBLK * NGRAPH * 2 * 4);
    int*   pcnt   = (int*)  carve((size_t)POOLBLK * NGRAPH * 4);
    float* Weff   = (float*)carve(D * 2 * 4);
    float* beff   = (float*)carve(2 * 4);

    const int nb = (n16 + SCAN_EPB - 1) / SCAN_EPB;   // 782 <= 1024
    const int nbuckets = (n >> BSHIFT) + 1;           // 13 for n=100000

    hipMemsetAsync(deg, 0, (size_t)n16 * 4, stream);

    k_count<<<(E / 4 + 255) / 256, 256, 0, stream>>>(src, dst, deg, rank, E);
    k_scan_a<<<nb, 256, 0, stream>>>(deg, offs, bsum, n16);
    k_scan_b<<<1, 1024, 0, stream>>>(bsum, nb);
    k_finalize<<<(n16 + 255) / 256, 256, 0, stream>>>(offs, bsum, deg, dinv, n);
    k_fill2<<<(E + CHUNK - 1) / CHUNK, 256, 0, stream>>>(src, dst, rank, offs, csr, E, nbuckets);
    k_foldW<<<1, 256, 0, stream>>>(W2, Wc, b2, bc, Weff, beff);

    // layer 1 GEMM: xW1 (bf16 out)
    k_gemm128<<<(n + GBM - 1) / GBM, 256, 0, stream>>>(x, W1, bufBF, n);
    // layer-1 agg + relu + project to z
    k_agg_proj<<<(n + 3) / 4, 256, 0, stream>>>(bufBF, offs, csr, dinv, b1, Weff, z, n, E);

    // fused layer-2 agg + mean-pool on z (raw edge stream, no CSR)
    k_pool_edges<<<POOLBLK, 256, 0, stream>>>(z, src, dst, dinv, batch, part, pcnt, n, E);
    k_finalpool<<<1, 256, 0, stream>>>(part, pcnt, beff, bc, (float*)d_out);
}

// Round 9
// 360.697 us; speedup vs baseline: 7.9727x; 1.4147x over previous
//
#include <hip/hip_runtime.h>
#include <hip/hip_bf16.h>

#define D 128
#define NGRAPH 64
#define POOLBLK 1024    // blocks in k_pool_edges
#define PBCHUNK 4096    // edges per block in k_part
#define WINSZ 256       // nodes per dst-window
#define WINSLOTS 16384  // edge slots per window (mean ~8184, 2x headroom)

__device__ __forceinline__ unsigned short f2bf(float f) {
    union { float f; unsigned int i; } u; u.f = f;
    unsigned int r = u.i + 0x7fffu + ((u.i >> 16) & 1u);   // round-to-nearest-even
    return (unsigned short)(r >> 16);
}
__device__ __forceinline__ float2 bf2_to_f2(unsigned int u) {
    union { unsigned int i; float f; } a, b;
    a.i = u << 16;            // low ushort  = element 0
    b.i = u & 0xffff0000u;    // high ushort = element 1
    return make_float2(a.f, b.f);
}

// ---------------- CSR build: windowed counting sort, no per-edge global atomics

// partition edges into nb dst-windows; ebuf[bin*WINSLOTS + pos] = src | (dst&255)<<17
__global__ __launch_bounds__(256) void k_part(const int* __restrict__ src,
                                              const int* __restrict__ dst,
                                              int* __restrict__ cursor,
                                              unsigned* __restrict__ ebuf,
                                              int E, int nb) {
    __shared__ unsigned spack[PBCHUNK];
    __shared__ unsigned short sbin[PBCHUNK];
    __shared__ unsigned short slrank[PBCHUNK];
    __shared__ int hist[400];
    __shared__ int base[400];
    int tid = threadIdx.x;
    for (int i = tid; i < nb; i += 256) hist[i] = 0;
    __syncthreads();
    int b0 = blockIdx.x * PBCHUNK;
    int cnt = min(PBCHUNK, E - b0);
    for (int j = tid; j < cnt; j += 256) {
        int s = __builtin_nontemporal_load(&src[b0 + j]);
        int d = __builtin_nontemporal_load(&dst[b0 + j]);
        int bin = d >> 8;
        spack[j] = (unsigned)s | ((unsigned)(d & 255) << 17);
        sbin[j] = (unsigned short)bin;
        slrank[j] = (unsigned short)atomicAdd(&hist[bin], 1);
    }
    __syncthreads();
    for (int i = tid; i < nb; i += 256)
        base[i] = hist[i] ? atomicAdd(&cursor[i], hist[i]) : 0;
    __syncthreads();
    for (int j = tid; j < cnt; j += 256) {
        int bin = sbin[j];
        ebuf[(size_t)bin * WINSLOTS + base[bin] + slrank[j]] = spack[j];
    }
}

// one block per window: LDS histogram -> deg/dinv/offcnt, LDS scan, rank pass -> csr
__global__ __launch_bounds__(256) void k_csrwin(const unsigned* __restrict__ ebuf,
                                                const int* __restrict__ cursor,
                                                int* __restrict__ csr,
                                                int2* __restrict__ offcnt,
                                                float* __restrict__ dinv, int n) {
    __shared__ int hist[WINSZ];
    __shared__ int lscan[WINSZ];
    __shared__ int sexcl[WINSZ];
    int b = blockIdx.x;
    int tid = threadIdx.x;
    hist[tid] = 0;
    __syncthreads();
    int cnt = cursor[b];
    const unsigned* eb = ebuf + (size_t)b * WINSLOTS;
    for (int j = tid; j < cnt; j += 256)
        atomicAdd(&hist[eb[j] >> 17], 1);
    __syncthreads();
    int deg = hist[tid];
    lscan[tid] = deg;
    __syncthreads();
    for (int off = 1; off < 256; off <<= 1) {
        int y = (tid >= off) ? lscan[tid - off] : 0;
        __syncthreads();
        lscan[tid] += y;
        __syncthreads();
    }
    int excl = lscan[tid] - deg;
    int v = b * WINSZ + tid;
    int gbase = b * WINSLOTS;
    if (v < n) {
        offcnt[v] = make_int2(gbase + excl, deg);
        dinv[v] = rsqrtf((float)(deg + 1));
    }
    hist[tid] = 0;
    sexcl[tid] = excl;
    __syncthreads();
    for (int j = tid; j < cnt; j += 256) {
        unsigned p = eb[j];
        int d8 = (int)(p >> 17);
        int lr = atomicAdd(&hist[d8], 1);
        csr[gbase + sexcl[d8] + lr] = (int)(p & 0x1FFFFu);
    }
}

// ---------------- dense GEMM: H = X @ W  (M x 128 @ 128 x 128, fp32 in, bf16 out)

#define GBM 64
#define GBK 32
__global__ __launch_bounds__(256) void k_gemm128(const float* __restrict__ X,
                                                 const float* __restrict__ W,
                                                 unsigned short* __restrict__ H, int nrows) {
    __shared__ float xs[GBM][GBK + 1];
    __shared__ float ws[GBK][D];
    int tid = threadIdx.x;
    int tc = tid & 31;
    int tr = tid >> 5;
    int m0 = blockIdx.x * GBM;
    float acc[8][4] = {};
    for (int kk = 0; kk < D; kk += GBK) {
        for (int i = tid; i < GBM * GBK; i += 256) {
            int r = i >> 5, c = i & 31;
            int gr = m0 + r;
            xs[r][c] = (gr < nrows) ? X[(size_t)gr * D + kk + c] : 0.f;
        }
        for (int i = tid; i < GBK * D; i += 256) {
            int r = i >> 7, c = i & 127;
            ws[r][c] = W[(size_t)(kk + r) * D + c];
        }
        __syncthreads();
#pragma unroll 4
        for (int k = 0; k < GBK; ++k) {
            float a[8];
#pragma unroll
            for (int ri = 0; ri < 8; ++ri) a[ri] = xs[tr * 8 + ri][k];
            float4 bv = *(const float4*)&ws[k][tc * 4];
            float b[4] = {bv.x, bv.y, bv.z, bv.w};
#pragma unroll
            for (int ri = 0; ri < 8; ++ri)
#pragma unroll
                for (int ci = 0; ci < 4; ++ci)
                    acc[ri][ci] += a[ri] * b[ci];
        }
        __syncthreads();
    }
#pragma unroll
    for (int ri = 0; ri < 8; ++ri) {
        int gr = m0 + tr * 8 + ri;
        if (gr < nrows) {
            ushort4 v;
            v.x = f2bf(acc[ri][0]); v.y = f2bf(acc[ri][1]);
            v.z = f2bf(acc[ri][2]); v.w = f2bf(acc[ri][3]);
            *(ushort4*)&H[(size_t)gr * D + tc * 4] = v;
        }
    }
}

// ---------------- layer-1 agg + relu + 2-dim projection ------------------
// z[v] = relu(agg1(xW1)[v] + b1) @ Weff   (fp32, 8B per node)

__global__ __launch_bounds__(256) void k_agg_proj(const unsigned short* __restrict__ H,
                                                  const int2* __restrict__ offcnt,
                                                  const int* __restrict__ csr,
                                                  const float* __restrict__ dinv,
                                                  const float* __restrict__ bias,
                                                  const float* __restrict__ Weff,
                                                  float2* __restrict__ z, int n) {
    int wid = threadIdx.x >> 6;
    int lane = threadIdx.x & 63;
    int v = blockIdx.x * 4 + wid;
    if (v >= n) return;
    float dv = dinv[v];
    int l2 = lane * 2;
    unsigned us = *(const unsigned*)(H + (size_t)v * D + l2);
    float2 hs = bf2_to_f2(us);
    float dv2 = dv * dv;
    float2 acc = make_float2(hs.x * dv2, hs.y * dv2);
    int2 oc = offcnt[v];
    int e = oc.x, eE = oc.x + oc.y;
    for (; e + 3 < eE; e += 4) {
        int s0 = csr[e], s1 = csr[e + 1], s2 = csr[e + 2], s3 = csr[e + 3];
        unsigned u0 = *(const unsigned*)(H + (size_t)s0 * D + l2);
        unsigned u1 = *(const unsigned*)(H + (size_t)s1 * D + l2);
        unsigned u2 = *(const unsigned*)(H + (size_t)s2 * D + l2);
        unsigned u3 = *(const unsigned*)(H + (size_t)s3 * D + l2);
        float w0 = dinv[s0] * dv, w1 = dinv[s1] * dv;
        float w2 = dinv[s2] * dv, w3 = dinv[s3] * dv;
        float2 h0 = bf2_to_f2(u0), h1 = bf2_to_f2(u1);
        float2 h2 = bf2_to_f2(u2), h3 = bf2_to_f2(u3);
        acc.x += h0.x * w0; acc.y += h0.y * w0;
        acc.x += h1.x * w1; acc.y += h1.y * w1;
        acc.x += h2.x * w2; acc.y += h2.y * w2;
        acc.x += h3.x * w3; acc.y += h3.y * w3;
    }
    for (; e < eE; ++e) {
        int s0 = csr[e];
        float w0 = dinv[s0] * dv;
        unsigned u0 = *(const unsigned*)(H + (size_t)s0 * D + l2);
        float2 h0 = bf2_to_f2(u0);
        acc.x += h0.x * w0; acc.y += h0.y * w0;
    }
    float2 b = ((const float2*)bias)[lane];
    acc.x = fmaxf(acc.x + b.x, 0.f);
    acc.y = fmaxf(acc.y + b.y, 0.f);
    float4 wv = *(const float4*)&Weff[l2 * 2];
    float z0 = acc.x * wv.x + acc.y * wv.z;
    float z1 = acc.x * wv.y + acc.y * wv.w;
#pragma unroll
    for (int off = 32; off >= 1; off >>= 1) {
        z0 += __shfl_xor(z0, off, 64);
        z1 += __shfl_xor(z1, off, 64);
    }
    if (lane == 0) z[v] = make_float2(z0, z1);
}

// ---------------- fused layer-2 agg + mean-pool on projected z -----------

__global__ __launch_bounds__(256) void k_pool_edges(const float2* __restrict__ z,
                                                    const int* __restrict__ src,
                                                    const int* __restrict__ dst,
                                                    const float* __restrict__ dinv,
                                                    const int* __restrict__ batch,
                                                    float* __restrict__ part,
                                                    int* __restrict__ pcnt,
                                                    int n, int E) {
    __shared__ float t[NGRAPH * 2];
    __shared__ int scnt[NGRAPH];
    int tid = threadIdx.x;
    if (tid < NGRAPH * 2) t[tid] = 0.f;
    if (tid < NGRAPH) scnt[tid] = 0;
    __syncthreads();

    int i = (blockIdx.x * 256 + tid) * 4;
    int stride = POOLBLK * 256 * 4;
    for (; i < E; i += stride) {
        if (i + 3 < E) {
            int4 s4 = *(const int4*)&src[i];
            int4 d4 = *(const int4*)&dst[i];
            float w0 = dinv[s4.x] * dinv[d4.x];
            float w1 = dinv[s4.y] * dinv[d4.y];
            float w2 = dinv[s4.z] * dinv[d4.z];
            float w3 = dinv[s4.w] * dinv[d4.w];
            float2 z0 = z[s4.x], z1 = z[s4.y], z2 = z[s4.z], z3 = z[s4.w];
            int g0 = batch[d4.x], g1 = batch[d4.y], g2 = batch[d4.z], g3 = batch[d4.w];
            atomicAdd(&t[g0 * 2],     w0 * z0.x);
            atomicAdd(&t[g0 * 2 + 1], w0 * z0.y);
            atomicAdd(&t[g1 * 2],     w1 * z1.x);
            atomicAdd(&t[g1 * 2 + 1], w1 * z1.y);
            atomicAdd(&t[g2 * 2],     w2 * z2.x);
            atomicAdd(&t[g2 * 2 + 1], w2 * z2.y);
            atomicAdd(&t[g3 * 2],     w3 * z3.x);
            atomicAdd(&t[g3 * 2 + 1], w3 * z3.y);
        } else {
            for (int j = i; j < E; ++j) {
                int s = src[j], d = dst[j];
                float w = dinv[s] * dinv[d];
                float2 zv = z[s];
                int g = batch[d];
                atomicAdd(&t[g * 2],     w * zv.x);
                atomicAdd(&t[g * 2 + 1], w * zv.y);
            }
        }
    }
    for (int v = blockIdx.x * 256 + tid; v < n; v += POOLBLK * 256) {
        float dv = dinv[v];
        float2 zv = z[v];
        int g = batch[v];
        float w = dv * dv;
        atomicAdd(&t[g * 2],     w * zv.x);
        atomicAdd(&t[g * 2 + 1], w * zv.y);
        atomicAdd(&scnt[g], 1);
    }
    __syncthreads();
    if (tid < NGRAPH * 2) part[blockIdx.x * (NGRAPH * 2) + tid] = t[tid];
    if (tid < NGRAPH) pcnt[blockIdx.x * NGRAPH + tid] = scnt[tid];
}

// Weff = W2 @ Wc (128x2), beff = b2 @ Wc + bc (2)
__global__ void k_foldW(const float* __restrict__ W2, const float* __restrict__ Wc,
                        const float* __restrict__ b2, const float* __restrict__ bc,
                        float* __restrict__ Weff, float* __restrict__ beff) {
    int t = threadIdx.x;
    int i = t >> 1, c = t & 1;
    float acc = 0.f;
    for (int k = 0; k < D; ++k) acc += W2[i * D + k] * Wc[k * 2 + c];
    Weff[i * 2 + c] = acc;
    if (i == 0) {
        float s = 0.f;
        for (int k = 0; k < D; ++k) s += b2[k] * Wc[k * 2 + c];
        beff[c] = s + bc[c];
    }
}

__global__ __launch_bounds__(256) void k_finalpool(const float* __restrict__ part,
                                                   const int* __restrict__ pcnt,
                                                   const float* __restrict__ beff,
                                                   const float* __restrict__ bc,
                                                   float* __restrict__ out) {
    __shared__ float tz[NGRAPH * 2];
    __shared__ int tc[NGRAPH];
    int tid = threadIdx.x;
    if (tid < NGRAPH * 2) {
        float s0 = 0.f, s1 = 0.f, s2 = 0.f, s3 = 0.f;
        int b = 0;
        for (; b + 3 < POOLBLK; b += 4) {
            s0 += part[(b + 0) * (NGRAPH * 2) + tid];
            s1 += part[(b + 1) * (NGRAPH * 2) + tid];
            s2 += part[(b + 2) * (NGRAPH * 2) + tid];
            s3 += part[(b + 3) * (NGRAPH * 2) + tid];
        }
        for (; b < POOLBLK; ++b) s0 += part[b * (NGRAPH * 2) + tid];
        tz[tid] = (s0 + s1) + (s2 + s3);
    } else if (tid < NGRAPH * 2 + NGRAPH) {
        int g = tid - NGRAPH * 2;
        int s0 = 0, s1 = 0, s2 = 0, s3 = 0;
        int b = 0;
        for (; b + 3 < POOLBLK; b += 4) {
            s0 += pcnt[(b + 0) * NGRAPH + g];
            s1 += pcnt[(b + 1) * NGRAPH + g];
            s2 += pcnt[(b + 2) * NGRAPH + g];
            s3 += pcnt[(b + 3) * NGRAPH + g];
        }
        for (; b < POOLBLK; ++b) s0 += pcnt[b * NGRAPH + g];
        tc[g] = (s0 + s1) + (s2 + s3);
    }
    __syncthreads();
    if (tid < NGRAPH * 2) {
        int g = tid >> 1, c = tid & 1;
        int cg = tc[g];
        out[tid] = cg ? (tz[tid] / (float)cg + beff[c]) : bc[c];
    }
}

// ---------------- launch ----------------

extern "C" void kernel_launch(void* const* d_in, const int* in_sizes, int n_in,
                              void* d_out, int out_size, void* d_ws, size_t ws_size,
                              hipStream_t stream) {
    const float* x    = (const float*)d_in[0];
    const int*   ei   = (const int*)d_in[1];
    const int*   batch= (const int*)d_in[2];
    const float* W1   = (const float*)d_in[3];
    const float* b1   = (const float*)d_in[4];
    const float* W2   = (const float*)d_in[5];
    const float* b2   = (const float*)d_in[6];
    const float* Wc   = (const float*)d_in[7];
    const float* bc   = (const float*)d_in[8];

    const int n = in_sizes[0] / D;       // 100000
    const int E = in_sizes[1] / 2;       // 3200000
    const int* src = ei;
    const int* dst = ei + E;
    const int nb = (n + WINSZ - 1) / WINSZ;   // 391 dst-windows

    char* ws = (char*)d_ws;
    size_t off = 0;
    auto carve = [&](size_t bytes) -> char* {
        char* p = ws + off;
        off = (off + bytes + 255) & ~(size_t)255;
        return p;
    };
    unsigned short* bufBF = (unsigned short*)carve((size_t)n * D * 2);   // xW1 (bf16)
    float2* z     = (float2*)carve((size_t)n * 8);                       // projected h1
    unsigned* ebuf= (unsigned*)carve((size_t)nb * WINSLOTS * 4);         // windowed edges
    int*   csr    = (int*)  carve((size_t)nb * WINSLOTS * 4);            // windowed CSR
    int*   cursor = (int*)  carve(512 * 4);
    int2*  offcnt = (int2*) carve((size_t)n * 8);
    float* dinv   = (float*)carve((size_t)n * 4);
    float* part   = (float*)carve((size_t)POOLBLK * NGRAPH * 2 * 4);
    int*   pcnt   = (int*)  carve((size_t)POOLBLK * NGRAPH * 4);
    float* Weff   = (float*)carve(D * 2 * 4);
    float* beff   = (float*)carve(2 * 4);

    hipMemsetAsync(cursor, 0, 512 * 4, stream);

    // CSR build (windowed counting sort)
    k_part<<<(E + PBCHUNK - 1) / PBCHUNK, 256, 0, stream>>>(src, dst, cursor, ebuf, E, nb);
    k_csrwin<<<nb, 256, 0, stream>>>(ebuf, cursor, csr, offcnt, dinv, n);
    k_foldW<<<1, 256, 0, stream>>>(W2, Wc, b2, bc, Weff, beff);

    // layer 1 GEMM: xW1 (bf16 out)
    k_gemm128<<<(n + GBM - 1) / GBM, 256, 0, stream>>>(x, W1, bufBF, n);
    // layer-1 agg + relu + project to z
    k_agg_proj<<<(n + 3) / 4, 256, 0, stream>>>(bufBF, offcnt, csr, dinv, b1, Weff, z, n);

    // fused layer-2 agg + mean-pool on z (raw edge stream)
    k_pool_edges<<<POOLBLK, 256, 0, stream>>>(z, src, dst, dinv, batch, part, pcnt, n, E);
    k_finalpool<<<1, 256, 0, stream>>>(part, pcnt, beff, bc, (float*)d_out);
}

// Round 10
// 305.906 us; speedup vs baseline: 9.4006x; 1.1791x over previous
//
#include <hip/hip_runtime.h>
#include <hip/hip_bf16.h>

#define D 128
#define NGRAPH 64
#define POOLBLK 256     // blocks in k_pool_edges
#define PBCHUNK 4096    // edges per block in k_part
#define WINSZ 256       // nodes per dst-window
#define WINSLOTS 16384  // edge slots per window (mean ~8184, 2x headroom)
#define XP 136          // padded LDS row (bf16) -> 2-way bank aliasing only

typedef __attribute__((ext_vector_type(4))) float f32x4;
typedef __attribute__((ext_vector_type(8))) short bf16x8;

__device__ __forceinline__ unsigned short f2bf(float f) {
    union { float f; unsigned int i; } u; u.f = f;
    unsigned int r = u.i + 0x7fffu + ((u.i >> 16) & 1u);   // round-to-nearest-even
    return (unsigned short)(r >> 16);
}
__device__ __forceinline__ float2 bf2_to_f2(unsigned int u) {
    union { unsigned int i; float f; } a, b;
    a.i = u << 16;            // low ushort  = element 0
    b.i = u & 0xffff0000u;    // high ushort = element 1
    return make_float2(a.f, b.f);
}

// ---------------- CSR build: windowed counting sort, no per-edge global atomics

__global__ __launch_bounds__(256) void k_part(const int* __restrict__ src,
                                              const int* __restrict__ dst,
                                              int* __restrict__ cursor,
                                              unsigned* __restrict__ ebuf,
                                              int E, int nb) {
    __shared__ unsigned spack[PBCHUNK];
    __shared__ unsigned short sbin[PBCHUNK];
    __shared__ unsigned short slrank[PBCHUNK];
    __shared__ int hist[400];
    __shared__ int base[400];
    int tid = threadIdx.x;
    for (int i = tid; i < nb; i += 256) hist[i] = 0;
    __syncthreads();
    int b0 = blockIdx.x * PBCHUNK;
    int cnt = min(PBCHUNK, E - b0);
    for (int j = tid; j < cnt; j += 256) {
        int s = __builtin_nontemporal_load(&src[b0 + j]);
        int d = __builtin_nontemporal_load(&dst[b0 + j]);
        int bin = d >> 8;
        spack[j] = (unsigned)s | ((unsigned)(d & 255) << 17);
        sbin[j] = (unsigned short)bin;
        slrank[j] = (unsigned short)atomicAdd(&hist[bin], 1);
    }
    __syncthreads();
    for (int i = tid; i < nb; i += 256)
        base[i] = hist[i] ? atomicAdd(&cursor[i], hist[i]) : 0;
    __syncthreads();
    for (int j = tid; j < cnt; j += 256) {
        int bin = sbin[j];
        ebuf[(size_t)bin * WINSLOTS + base[bin] + slrank[j]] = spack[j];
    }
}

__global__ __launch_bounds__(256) void k_csrwin(const unsigned* __restrict__ ebuf,
                                                const int* __restrict__ cursor,
                                                int* __restrict__ csr,
                                                int2* __restrict__ offcnt,
                                                float* __restrict__ dinv, int n) {
    __shared__ int hist[WINSZ];
    __shared__ int lscan[WINSZ];
    __shared__ int sexcl[WINSZ];
    int b = blockIdx.x;
    int tid = threadIdx.x;
    hist[tid] = 0;
    __syncthreads();
    int cnt = cursor[b];
    const unsigned* eb = ebuf + (size_t)b * WINSLOTS;
    for (int j = tid; j < cnt; j += 256)
        atomicAdd(&hist[eb[j] >> 17], 1);
    __syncthreads();
    int deg = hist[tid];
    lscan[tid] = deg;
    __syncthreads();
    for (int off = 1; off < 256; off <<= 1) {
        int y = (tid >= off) ? lscan[tid - off] : 0;
        __syncthreads();
        lscan[tid] += y;
        __syncthreads();
    }
    int excl = lscan[tid] - deg;
    int v = b * WINSZ + tid;
    int gbase = b * WINSLOTS;
    if (v < n) {
        offcnt[v] = make_int2(gbase + excl, deg);
        dinv[v] = rsqrtf((float)(deg + 1));
    }
    hist[tid] = 0;
    sexcl[tid] = excl;
    __syncthreads();
    for (int j = tid; j < cnt; j += 256) {
        unsigned p = eb[j];
        int d8 = (int)(p >> 17);
        int lr = atomicAdd(&hist[d8], 1);
        csr[gbase + sexcl[d8] + lr] = (int)(p & 0x1FFFFu);
    }
}

// ---------------- prep: Weff = W2@Wc, beff = b2@Wc + bc, W1bfT[n][k] = bf16(W1[k][n])

__global__ __launch_bounds__(256) void k_prep(const float* __restrict__ W1,
                                              const float* __restrict__ W2,
                                              const float* __restrict__ Wc,
                                              const float* __restrict__ b2,
                                              const float* __restrict__ bc,
                                              float* __restrict__ Weff,
                                              float* __restrict__ beff,
                                              unsigned short* __restrict__ W1bfT) {
    int t = threadIdx.x;
    int i = t >> 1, c = t & 1;
    float acc = 0.f;
    for (int k = 0; k < D; ++k) acc += W2[i * D + k] * Wc[k * 2 + c];
    Weff[i * 2 + c] = acc;
    if (i == 0) {
        float s = 0.f;
        for (int k = 0; k < D; ++k) s += b2[k] * Wc[k * 2 + c];
        beff[c] = s + bc[c];
    }
    // transpose-convert W1 (16384 elements, 64 per thread)
    for (int e = t; e < D * D; e += 256) {
        int n = e >> 7, k = e & 127;
        W1bfT[n * D + k] = f2bf(W1[k * D + n]);
    }
}

// ---------------- MFMA bf16 GEMM: H = bf16(X) @ bf16(W1), bf16 out ------
// A frag (16x16x32): lane l -> row=l&15, k=8*(l>>4)+j ; B: col=l&15, k same
// C/D: col=lane&15, row=4*(lane>>4)+reg   [m89-verified]

__global__ __launch_bounds__(256) void k_gemm_mfma(const float* __restrict__ X,
                                                   const unsigned short* __restrict__ W1bfT,
                                                   unsigned short* __restrict__ H, int nrows) {
    __shared__ unsigned short xs[64][XP];    // X tile, bf16
    __shared__ unsigned short wt[128][XP];   // W^T: wt[n][k]
    int tid = threadIdx.x;
    int m0 = blockIdx.x * 64;
    // stage W^T (32KB, L2-resident re-read)
    {
        const uint4* wsrc = (const uint4*)W1bfT;       // [128][128] u16
        for (int i = tid; i < 2048; i += 256) {
            uint4 v = wsrc[i];
            int elt = i * 8;
            int r = elt >> 7, c = elt & 127;
            *(uint4*)&wt[r][c] = v;
        }
    }
    // stage X tile (convert fp32 -> bf16)
    {
        for (int i = tid; i < 2048; i += 256) {        // 2048 float4 loads
            int elt = i * 4;
            int r = elt >> 7, c = elt & 127;
            int gr = m0 + r;
            float4 v = (gr < nrows) ? *(const float4*)&X[(size_t)gr * D + c]
                                    : make_float4(0.f, 0.f, 0.f, 0.f);
            ushort4 bv;
            bv.x = f2bf(v.x); bv.y = f2bf(v.y); bv.z = f2bf(v.z); bv.w = f2bf(v.w);
            *(ushort4*)&xs[r][c] = bv;
        }
    }
    __syncthreads();
    int wv = tid >> 6, lane = tid & 63;
    int lrow = lane & 15, lk = (lane >> 4) * 8;
    f32x4 acc[8];
#pragma unroll
    for (int i = 0; i < 8; ++i) acc[i] = (f32x4){0.f, 0.f, 0.f, 0.f};
#pragma unroll
    for (int kk = 0; kk < 128; kk += 32) {
        bf16x8 a = *(bf16x8*)&xs[wv * 16 + lrow][kk + lk];
#pragma unroll
        for (int nt = 0; nt < 8; ++nt) {
            bf16x8 b = *(bf16x8*)&wt[nt * 16 + lrow][kk + lk];
            acc[nt] = __builtin_amdgcn_mfma_f32_16x16x32_bf16(a, b, acc[nt], 0, 0, 0);
        }
    }
    int orow = m0 + wv * 16 + (lane >> 4) * 4;
#pragma unroll
    for (int nt = 0; nt < 8; ++nt) {
#pragma unroll
        for (int r = 0; r < 4; ++r) {
            int gr = orow + r;
            if (gr < nrows) H[(size_t)gr * D + nt * 16 + lrow] = f2bf(acc[nt][r]);
        }
    }
}

// ---------------- layer-1 agg + relu + 2-dim projection ------------------

__global__ __launch_bounds__(256) void k_agg_proj(const unsigned short* __restrict__ H,
                                                  const int2* __restrict__ offcnt,
                                                  const int* __restrict__ csr,
                                                  const float* __restrict__ dinv,
                                                  const float* __restrict__ bias,
                                                  const float* __restrict__ Weff,
                                                  float2* __restrict__ z, int n) {
    int wid = threadIdx.x >> 6;
    int lane = threadIdx.x & 63;
    int v = blockIdx.x * 4 + wid;
    if (v >= n) return;
    float dv = dinv[v];
    int l2 = lane * 2;
    unsigned us = *(const unsigned*)(H + (size_t)v * D + l2);
    float2 hs = bf2_to_f2(us);
    float dv2 = dv * dv;
    float2 acc = make_float2(hs.x * dv2, hs.y * dv2);
    int2 oc = offcnt[v];
    int e = oc.x, eE = oc.x + oc.y;
    for (; e + 3 < eE; e += 4) {
        int s0 = csr[e], s1 = csr[e + 1], s2 = csr[e + 2], s3 = csr[e + 3];
        unsigned u0 = *(const unsigned*)(H + (size_t)s0 * D + l2);
        unsigned u1 = *(const unsigned*)(H + (size_t)s1 * D + l2);
        unsigned u2 = *(const unsigned*)(H + (size_t)s2 * D + l2);
        unsigned u3 = *(const unsigned*)(H + (size_t)s3 * D + l2);
        float w0 = dinv[s0] * dv, w1 = dinv[s1] * dv;
        float w2 = dinv[s2] * dv, w3 = dinv[s3] * dv;
        float2 h0 = bf2_to_f2(u0), h1 = bf2_to_f2(u1);
        float2 h2 = bf2_to_f2(u2), h3 = bf2_to_f2(u3);
        acc.x += h0.x * w0; acc.y += h0.y * w0;
        acc.x += h1.x * w1; acc.y += h1.y * w1;
        acc.x += h2.x * w2; acc.y += h2.y * w2;
        acc.x += h3.x * w3; acc.y += h3.y * w3;
    }
    for (; e < eE; ++e) {
        int s0 = csr[e];
        float w0 = dinv[s0] * dv;
        unsigned u0 = *(const unsigned*)(H + (size_t)s0 * D + l2);
        float2 h0 = bf2_to_f2(u0);
        acc.x += h0.x * w0; acc.y += h0.y * w0;
    }
    float2 b = ((const float2*)bias)[lane];
    acc.x = fmaxf(acc.x + b.x, 0.f);
    acc.y = fmaxf(acc.y + b.y, 0.f);
    float4 wv = *(const float4*)&Weff[l2 * 2];
    float z0 = acc.x * wv.x + acc.y * wv.z;
    float z1 = acc.x * wv.y + acc.y * wv.w;
#pragma unroll
    for (int off = 32; off >= 1; off >>= 1) {
        z0 += __shfl_xor(z0, off, 64);
        z1 += __shfl_xor(z1, off, 64);
    }
    if (lane == 0) z[v] = make_float2(z0, z1);
}

// ---------------- fused layer-2 agg + mean-pool on projected z -----------
// LDS accumulate per block, single global-atomic flush to tsum/cnt.

__global__ __launch_bounds__(256) void k_pool_edges(const float2* __restrict__ z,
                                                    const int* __restrict__ src,
                                                    const int* __restrict__ dst,
                                                    const float* __restrict__ dinv,
                                                    const int* __restrict__ batch,
                                                    float* __restrict__ tsum,
                                                    int* __restrict__ cnt,
                                                    int n, int E) {
    __shared__ float t[NGRAPH * 2];
    __shared__ int scnt[NGRAPH];
    int tid = threadIdx.x;
    if (tid < NGRAPH * 2) t[tid] = 0.f;
    if (tid < NGRAPH) scnt[tid] = 0;
    __syncthreads();

    int i = (blockIdx.x * 256 + tid) * 4;
    int stride = POOLBLK * 256 * 4;
    for (; i < E; i += stride) {
        if (i + 3 < E) {
            int4 s4 = *(const int4*)&src[i];
            int4 d4 = *(const int4*)&dst[i];
            float w0 = dinv[s4.x] * dinv[d4.x];
            float w1 = dinv[s4.y] * dinv[d4.y];
            float w2 = dinv[s4.z] * dinv[d4.z];
            float w3 = dinv[s4.w] * dinv[d4.w];
            float2 z0 = z[s4.x], z1 = z[s4.y], z2 = z[s4.z], z3 = z[s4.w];
            int g0 = batch[d4.x], g1 = batch[d4.y], g2 = batch[d4.z], g3 = batch[d4.w];
            atomicAdd(&t[g0 * 2],     w0 * z0.x);
            atomicAdd(&t[g0 * 2 + 1], w0 * z0.y);
            atomicAdd(&t[g1 * 2],     w1 * z1.x);
            atomicAdd(&t[g1 * 2 + 1], w1 * z1.y);
            atomicAdd(&t[g2 * 2],     w2 * z2.x);
            atomicAdd(&t[g2 * 2 + 1], w2 * z2.y);
            atomicAdd(&t[g3 * 2],     w3 * z3.x);
            atomicAdd(&t[g3 * 2 + 1], w3 * z3.y);
        } else {
            for (int j = i; j < E; ++j) {
                int s = src[j], d = dst[j];
                float w = dinv[s] * dinv[d];
                float2 zv = z[s];
                int g = batch[d];
                atomicAdd(&t[g * 2],     w * zv.x);
                atomicAdd(&t[g * 2 + 1], w * zv.y);
            }
        }
    }
    for (int v = blockIdx.x * 256 + tid; v < n; v += POOLBLK * 256) {
        float dv = dinv[v];
        float2 zv = z[v];
        int g = batch[v];
        float w = dv * dv;
        atomicAdd(&t[g * 2],     w * zv.x);
        atomicAdd(&t[g * 2 + 1], w * zv.y);
        atomicAdd(&scnt[g], 1);
    }
    __syncthreads();
    if (tid < NGRAPH * 2 && t[tid] != 0.f) atomicAdd(&tsum[tid], t[tid]);
    if (tid < NGRAPH && scnt[tid]) atomicAdd(&cnt[tid], scnt[tid]);
}

__global__ void k_classify(const float* __restrict__ tsum, const int* __restrict__ cnt,
                           const float* __restrict__ beff, const float* __restrict__ bc,
                           float* __restrict__ out) {
    int t = threadIdx.x;
    if (t >= NGRAPH * 2) return;
    int g = t >> 1, c = t & 1;
    int cg = cnt[g];
    out[t] = cg ? (tsum[t] / (float)cg + beff[c]) : bc[c];
}

// ---------------- launch ----------------

extern "C" void kernel_launch(void* const* d_in, const int* in_sizes, int n_in,
                              void* d_out, int out_size, void* d_ws, size_t ws_size,
                              hipStream_t stream) {
    const float* x    = (const float*)d_in[0];
    const int*   ei   = (const int*)d_in[1];
    const int*   batch= (const int*)d_in[2];
    const float* W1   = (const float*)d_in[3];
    const float* b1   = (const float*)d_in[4];
    const float* W2   = (const float*)d_in[5];
    const float* b2   = (const float*)d_in[6];
    const float* Wc   = (const float*)d_in[7];
    const float* bc   = (const float*)d_in[8];

    const int n = in_sizes[0] / D;       // 100000
    const int E = in_sizes[1] / 2;       // 3200000
    const int* src = ei;
    const int* dst = ei + E;
    const int nb = (n + WINSZ - 1) / WINSZ;   // 391 dst-windows

    char* ws = (char*)d_ws;
    size_t off = 0;
    auto carve = [&](size_t bytes) -> char* {
        char* p = ws + off;
        off = (off + bytes + 255) & ~(size_t)255;
        return p;
    };
    unsigned short* bufBF = (unsigned short*)carve((size_t)n * D * 2);   // xW1 (bf16)
    float2* z     = (float2*)carve((size_t)n * 8);                       // projected h1
    unsigned* ebuf= (unsigned*)carve((size_t)nb * WINSLOTS * 4);         // windowed edges
    int*   csr    = (int*)  carve((size_t)nb * WINSLOTS * 4);            // windowed CSR
    // zero-region: cursor | tsum | cnt  (one memset)
    int*   cursor = (int*)  carve((512 + NGRAPH * 2 + NGRAPH) * 4);
    float* tsum   = (float*)(cursor + 512);
    int*   cnt    = (int*)  (tsum + NGRAPH * 2);
    int2*  offcnt = (int2*) carve((size_t)n * 8);
    float* dinv   = (float*)carve((size_t)n * 4);
    float* Weff   = (float*)carve(D * 2 * 4);
    float* beff   = (float*)carve(2 * 4);
    unsigned short* W1bfT = (unsigned short*)carve(D * D * 2);

    hipMemsetAsync(cursor, 0, (512 + NGRAPH * 2 + NGRAPH) * 4, stream);

    // CSR build (windowed counting sort)
    k_part<<<(E + PBCHUNK - 1) / PBCHUNK, 256, 0, stream>>>(src, dst, cursor, ebuf, E, nb);
    k_csrwin<<<nb, 256, 0, stream>>>(ebuf, cursor, csr, offcnt, dinv, n);
    k_prep<<<1, 256, 0, stream>>>(W1, W2, Wc, b2, bc, Weff, beff, W1bfT);

    // layer 1 GEMM (MFMA bf16): xW1 -> bufBF
    k_gemm_mfma<<<(n + 63) / 64, 256, 0, stream>>>(x, W1bfT, bufBF, n);
    // layer-1 agg + relu + project to z
    k_agg_proj<<<(n + 3) / 4, 256, 0, stream>>>(bufBF, offcnt, csr, dinv, b1, Weff, z, n);

    // fused layer-2 agg + mean-pool on z (raw edge stream)
    k_pool_edges<<<POOLBLK, 256, 0, stream>>>(z, src, dst, dinv, batch, tsum, cnt, n, E);
    k_classify<<<1, 128, 0, stream>>>(tsum, cnt, beff, bc, (float*)d_out);
}

// Round 11
// 290.095 us; speedup vs baseline: 9.9130x; 1.0545x over previous
//
#include <hip/hip_runtime.h>
#include <hip/hip_bf16.h>

#define D 128
#define NGRAPH 64
#define POOLBLK 256     // blocks in k_pool_edges
#define PBCHUNK 4096    // edges per block in k_part
#define WINSZ 256       // nodes per dst-window
#define WINSLOTS 16384  // edge slots per window (mean ~8184, 2x headroom)
#define XP 136          // padded LDS row (bf16) -> 2-way bank aliasing only

typedef __attribute__((ext_vector_type(4))) float f32x4;
typedef __attribute__((ext_vector_type(8))) short bf16x8;

__device__ __forceinline__ unsigned short f2bf(float f) {
    union { float f; unsigned int i; } u; u.f = f;
    unsigned int r = u.i + 0x7fffu + ((u.i >> 16) & 1u);   // round-to-nearest-even
    return (unsigned short)(r >> 16);
}
__device__ __forceinline__ float2 bf2_to_f2(unsigned int u) {
    union { unsigned int i; float f; } a, b;
    a.i = u << 16;            // low ushort  = element 0
    b.i = u & 0xffff0000u;    // high ushort = element 1
    return make_float2(a.f, b.f);
}

// ---------------- prep: Weff = W2@Wc, beff, and zero cursor/tsum/cnt -----

__global__ __launch_bounds__(256) void k_prep(const float* __restrict__ W2,
                                              const float* __restrict__ Wc,
                                              const float* __restrict__ b2,
                                              const float* __restrict__ bc,
                                              float* __restrict__ Weff,
                                              float* __restrict__ beff,
                                              int* __restrict__ zero_region,
                                              int zero_words) {
    int t = threadIdx.x;
    int i = t >> 1, c = t & 1;
    float acc = 0.f;
    for (int k = 0; k < D; ++k) acc += W2[i * D + k] * Wc[k * 2 + c];
    Weff[i * 2 + c] = acc;
    if (i == 0) {
        float s = 0.f;
        for (int k = 0; k < D; ++k) s += b2[k] * Wc[k * 2 + c];
        beff[c] = s + bc[c];
    }
    for (int j = t; j < zero_words; j += 256) zero_region[j] = 0;
}

// ---------------- CSR build: windowed counting sort ----------------------

__global__ __launch_bounds__(256) void k_part(const int* __restrict__ src,
                                              const int* __restrict__ dst,
                                              int* __restrict__ cursor,
                                              unsigned* __restrict__ ebuf,
                                              int E, int nb) {
    __shared__ unsigned spack[PBCHUNK];
    __shared__ unsigned short sbin[PBCHUNK];
    __shared__ unsigned short slrank[PBCHUNK];
    __shared__ int hist[400];
    __shared__ int base[400];
    int tid = threadIdx.x;
    for (int i = tid; i < nb; i += 256) hist[i] = 0;
    __syncthreads();
    int b0 = blockIdx.x * PBCHUNK;
    int cnt = min(PBCHUNK, E - b0);
    for (int j = tid; j < cnt; j += 256) {
        int s = __builtin_nontemporal_load(&src[b0 + j]);
        int d = __builtin_nontemporal_load(&dst[b0 + j]);
        int bin = d >> 8;
        spack[j] = (unsigned)s | ((unsigned)(d & 255) << 17);
        sbin[j] = (unsigned short)bin;
        slrank[j] = (unsigned short)atomicAdd(&hist[bin], 1);
    }
    __syncthreads();
    for (int i = tid; i < nb; i += 256)
        base[i] = hist[i] ? atomicAdd(&cursor[i], hist[i]) : 0;
    __syncthreads();
    for (int j = tid; j < cnt; j += 256) {
        int bin = sbin[j];
        ebuf[(size_t)bin * WINSLOTS + base[bin] + slrank[j]] = spack[j];
    }
}

__global__ __launch_bounds__(256) void k_csrwin(const unsigned* __restrict__ ebuf,
                                                const int* __restrict__ cursor,
                                                int* __restrict__ csr,
                                                int2* __restrict__ offcnt,
                                                float* __restrict__ dinv, int n) {
    __shared__ int hist[WINSZ];
    __shared__ int lscan[WINSZ];
    __shared__ int sexcl[WINSZ];
    int b = blockIdx.x;
    int tid = threadIdx.x;
    hist[tid] = 0;
    __syncthreads();
    int cnt = cursor[b];
    const unsigned* eb = ebuf + (size_t)b * WINSLOTS;
    for (int j = tid; j < cnt; j += 256)
        atomicAdd(&hist[eb[j] >> 17], 1);
    __syncthreads();
    int deg = hist[tid];
    lscan[tid] = deg;
    __syncthreads();
    for (int off = 1; off < 256; off <<= 1) {
        int y = (tid >= off) ? lscan[tid - off] : 0;
        __syncthreads();
        lscan[tid] += y;
        __syncthreads();
    }
    int excl = lscan[tid] - deg;
    int v = b * WINSZ + tid;
    int gbase = b * WINSLOTS;
    if (v < n) {
        offcnt[v] = make_int2(gbase + excl, deg);
        dinv[v] = rsqrtf((float)(deg + 1));
    }
    hist[tid] = 0;
    sexcl[tid] = excl;
    __syncthreads();
    for (int j = tid; j < cnt; j += 256) {
        unsigned p = eb[j];
        int d8 = (int)(p >> 17);
        int lr = atomicAdd(&hist[d8], 1);
        csr[gbase + sexcl[d8] + lr] = (int)(p & 0x1FFFFu);
    }
}

// ---------------- MFMA bf16 GEMM: H = bf16(X) @ bf16(W1), bf16 out ------
// W1 (fp32, row-major [k][n]) is converted+transposed into LDS in-kernel.
// A frag (16x16x32): lane l -> row=l&15, k=8*(l>>4)+j ; B: col=l&15, k same
// C/D: col=lane&15, row=4*(lane>>4)+reg   [m89-verified]

__global__ __launch_bounds__(256) void k_gemm_mfma(const float* __restrict__ X,
                                                   const float* __restrict__ W1,
                                                   unsigned short* __restrict__ H, int nrows) {
    __shared__ unsigned short xs[64][XP];    // X tile, bf16
    __shared__ unsigned short wt[128][XP];   // W^T: wt[n][k]
    int tid = threadIdx.x;
    int m0 = blockIdx.x * 64;
    // stage W^T: coalesced fp32 read of W1 row k, scattered LDS writes
    for (int i = tid; i < 2048; i += 256) {
        int elt = i * 8;
        int k = elt >> 7, n0 = elt & 127;            // W1[k][n0..n0+7]
        float4 a = *(const float4*)&W1[k * D + n0];
        float4 b = *(const float4*)&W1[k * D + n0 + 4];
        wt[n0 + 0][k] = f2bf(a.x); wt[n0 + 1][k] = f2bf(a.y);
        wt[n0 + 2][k] = f2bf(a.z); wt[n0 + 3][k] = f2bf(a.w);
        wt[n0 + 4][k] = f2bf(b.x); wt[n0 + 5][k] = f2bf(b.y);
        wt[n0 + 6][k] = f2bf(b.z); wt[n0 + 7][k] = f2bf(b.w);
    }
    // stage X tile (convert fp32 -> bf16)
    for (int i = tid; i < 2048; i += 256) {
        int elt = i * 4;
        int r = elt >> 7, c = elt & 127;
        int gr = m0 + r;
        float4 v = (gr < nrows) ? *(const float4*)&X[(size_t)gr * D + c]
                                : make_float4(0.f, 0.f, 0.f, 0.f);
        ushort4 bv;
        bv.x = f2bf(v.x); bv.y = f2bf(v.y); bv.z = f2bf(v.z); bv.w = f2bf(v.w);
        *(ushort4*)&xs[r][c] = bv;
    }
    __syncthreads();
    int wv = tid >> 6, lane = tid & 63;
    int lrow = lane & 15, lk = (lane >> 4) * 8;
    f32x4 acc[8];
#pragma unroll
    for (int i = 0; i < 8; ++i) acc[i] = (f32x4){0.f, 0.f, 0.f, 0.f};
#pragma unroll
    for (int kk = 0; kk < 128; kk += 32) {
        bf16x8 a = *(bf16x8*)&xs[wv * 16 + lrow][kk + lk];
#pragma unroll
        for (int nt = 0; nt < 8; ++nt) {
            bf16x8 b = *(bf16x8*)&wt[nt * 16 + lrow][kk + lk];
            acc[nt] = __builtin_amdgcn_mfma_f32_16x16x32_bf16(a, b, acc[nt], 0, 0, 0);
        }
    }
    int orow = m0 + wv * 16 + (lane >> 4) * 4;
#pragma unroll
    for (int nt = 0; nt < 8; ++nt) {
#pragma unroll
        for (int r = 0; r < 4; ++r) {
            int gr = orow + r;
            if (gr < nrows) H[(size_t)gr * D + nt * 16 + lrow] = f2bf(acc[nt][r]);
        }
    }
}

// ---------------- layer-1 agg + relu + 2-dim projection (8-deep ILP) -----

__global__ __launch_bounds__(256) void k_agg_proj(const unsigned short* __restrict__ H,
                                                  const int2* __restrict__ offcnt,
                                                  const int* __restrict__ csr,
                                                  const float* __restrict__ dinv,
                                                  const float* __restrict__ bias,
                                                  const float* __restrict__ Weff,
                                                  float2* __restrict__ z, int n) {
    int wid = threadIdx.x >> 6;
    int lane = threadIdx.x & 63;
    int v = blockIdx.x * 4 + wid;
    if (v >= n) return;
    float dv = dinv[v];
    int l2 = lane * 2;
    unsigned us = *(const unsigned*)(H + (size_t)v * D + l2);
    float2 hs = bf2_to_f2(us);
    float dv2 = dv * dv;
    float2 acc = make_float2(hs.x * dv2, hs.y * dv2);
    int2 oc = offcnt[v];
    int e = oc.x, eE = oc.x + oc.y;
    for (; e + 7 < eE; e += 8) {
        int s[8];
#pragma unroll
        for (int j = 0; j < 8; ++j) s[j] = csr[e + j];
        unsigned u[8];
#pragma unroll
        for (int j = 0; j < 8; ++j) u[j] = *(const unsigned*)(H + (size_t)s[j] * D + l2);
        float w[8];
#pragma unroll
        for (int j = 0; j < 8; ++j) w[j] = dinv[s[j]] * dv;
#pragma unroll
        for (int j = 0; j < 8; ++j) {
            float2 h = bf2_to_f2(u[j]);
            acc.x += h.x * w[j]; acc.y += h.y * w[j];
        }
    }
    for (; e + 3 < eE; e += 4) {
        int s0 = csr[e], s1 = csr[e + 1], s2 = csr[e + 2], s3 = csr[e + 3];
        unsigned u0 = *(const unsigned*)(H + (size_t)s0 * D + l2);
        unsigned u1 = *(const unsigned*)(H + (size_t)s1 * D + l2);
        unsigned u2 = *(const unsigned*)(H + (size_t)s2 * D + l2);
        unsigned u3 = *(const unsigned*)(H + (size_t)s3 * D + l2);
        float w0 = dinv[s0] * dv, w1 = dinv[s1] * dv;
        float w2 = dinv[s2] * dv, w3 = dinv[s3] * dv;
        float2 h0 = bf2_to_f2(u0), h1 = bf2_to_f2(u1);
        float2 h2 = bf2_to_f2(u2), h3 = bf2_to_f2(u3);
        acc.x += h0.x * w0; acc.y += h0.y * w0;
        acc.x += h1.x * w1; acc.y += h1.y * w1;
        acc.x += h2.x * w2; acc.y += h2.y * w2;
        acc.x += h3.x * w3; acc.y += h3.y * w3;
    }
    for (; e < eE; ++e) {
        int s0 = csr[e];
        float w0 = dinv[s0] * dv;
        unsigned u0 = *(const unsigned*)(H + (size_t)s0 * D + l2);
        float2 h0 = bf2_to_f2(u0);
        acc.x += h0.x * w0; acc.y += h0.y * w0;
    }
    float2 b = ((const float2*)bias)[lane];
    acc.x = fmaxf(acc.x + b.x, 0.f);
    acc.y = fmaxf(acc.y + b.y, 0.f);
    float4 wv = *(const float4*)&Weff[l2 * 2];
    float z0 = acc.x * wv.x + acc.y * wv.z;
    float z1 = acc.x * wv.y + acc.y * wv.w;
#pragma unroll
    for (int off = 32; off >= 1; off >>= 1) {
        z0 += __shfl_xor(z0, off, 64);
        z1 += __shfl_xor(z1, off, 64);
    }
    if (lane == 0) z[v] = make_float2(z0, z1);
}

// ---------------- fused layer-2 agg + mean-pool on projected z -----------
// per-wave private LDS accumulators (4x less same-address contention)

__global__ __launch_bounds__(256) void k_pool_edges(const float2* __restrict__ z,
                                                    const int* __restrict__ src,
                                                    const int* __restrict__ dst,
                                                    const float* __restrict__ dinv,
                                                    const int* __restrict__ batch,
                                                    float* __restrict__ tsum,
                                                    int* __restrict__ cnt,
                                                    int n, int E) {
    __shared__ float t[4][NGRAPH * 2];
    __shared__ int scnt[4][NGRAPH];
    int tid = threadIdx.x;
    int wv = tid >> 6;
    for (int j = tid; j < 4 * NGRAPH * 2; j += 256) ((float*)t)[j] = 0.f;
    for (int j = tid; j < 4 * NGRAPH; j += 256) ((int*)scnt)[j] = 0;
    __syncthreads();

    int i = (blockIdx.x * 256 + tid) * 4;
    int stride = POOLBLK * 256 * 4;
    for (; i < E; i += stride) {
        if (i + 3 < E) {
            int4 s4 = *(const int4*)&src[i];
            int4 d4 = *(const int4*)&dst[i];
            float w0 = dinv[s4.x] * dinv[d4.x];
            float w1 = dinv[s4.y] * dinv[d4.y];
            float w2 = dinv[s4.z] * dinv[d4.z];
            float w3 = dinv[s4.w] * dinv[d4.w];
            float2 z0 = z[s4.x], z1 = z[s4.y], z2 = z[s4.z], z3 = z[s4.w];
            int g0 = batch[d4.x], g1 = batch[d4.y], g2 = batch[d4.z], g3 = batch[d4.w];
            atomicAdd(&t[wv][g0 * 2],     w0 * z0.x);
            atomicAdd(&t[wv][g0 * 2 + 1], w0 * z0.y);
            atomicAdd(&t[wv][g1 * 2],     w1 * z1.x);
            atomicAdd(&t[wv][g1 * 2 + 1], w1 * z1.y);
            atomicAdd(&t[wv][g2 * 2],     w2 * z2.x);
            atomicAdd(&t[wv][g2 * 2 + 1], w2 * z2.y);
            atomicAdd(&t[wv][g3 * 2],     w3 * z3.x);
            atomicAdd(&t[wv][g3 * 2 + 1], w3 * z3.y);
        } else {
            for (int j = i; j < E; ++j) {
                int s = src[j], d = dst[j];
                float w = dinv[s] * dinv[d];
                float2 zv = z[s];
                int g = batch[d];
                atomicAdd(&t[wv][g * 2],     w * zv.x);
                atomicAdd(&t[wv][g * 2 + 1], w * zv.y);
            }
        }
    }
    for (int v = blockIdx.x * 256 + tid; v < n; v += POOLBLK * 256) {
        float dv = dinv[v];
        float2 zv = z[v];
        int g = batch[v];
        float w = dv * dv;
        atomicAdd(&t[wv][g * 2],     w * zv.x);
        atomicAdd(&t[wv][g * 2 + 1], w * zv.y);
        atomicAdd(&scnt[wv][g], 1);
    }
    __syncthreads();
    if (tid < NGRAPH * 2) {
        float s = t[0][tid] + t[1][tid] + t[2][tid] + t[3][tid];
        if (s != 0.f) atomicAdd(&tsum[tid], s);
    }
    if (tid < NGRAPH) {
        int s = scnt[0][tid] + scnt[1][tid] + scnt[2][tid] + scnt[3][tid];
        if (s) atomicAdd(&cnt[tid], s);
    }
}

__global__ void k_classify(const float* __restrict__ tsum, const int* __restrict__ cnt,
                           const float* __restrict__ beff, const float* __restrict__ bc,
                           float* __restrict__ out) {
    int t = threadIdx.x;
    if (t >= NGRAPH * 2) return;
    int g = t >> 1, c = t & 1;
    int cg = cnt[g];
    out[t] = cg ? (tsum[t] / (float)cg + beff[c]) : bc[c];
}

// ---------------- launch ----------------

extern "C" void kernel_launch(void* const* d_in, const int* in_sizes, int n_in,
                              void* d_out, int out_size, void* d_ws, size_t ws_size,
                              hipStream_t stream) {
    const float* x    = (const float*)d_in[0];
    const int*   ei   = (const int*)d_in[1];
    const int*   batch= (const int*)d_in[2];
    const float* W1   = (const float*)d_in[3];
    const float* b1   = (const float*)d_in[4];
    const float* W2   = (const float*)d_in[5];
    const float* b2   = (const float*)d_in[6];
    const float* Wc   = (const float*)d_in[7];
    const float* bc   = (const float*)d_in[8];

    const int n = in_sizes[0] / D;       // 100000
    const int E = in_sizes[1] / 2;       // 3200000
    const int* src = ei;
    const int* dst = ei + E;
    const int nb = (n + WINSZ - 1) / WINSZ;   // 391 dst-windows

    char* ws = (char*)d_ws;
    size_t off = 0;
    auto carve = [&](size_t bytes) -> char* {
        char* p = ws + off;
        off = (off + bytes + 255) & ~(size_t)255;
        return p;
    };
    unsigned short* bufBF = (unsigned short*)carve((size_t)n * D * 2);   // xW1 (bf16)
    float2* z     = (float2*)carve((size_t)n * 8);                       // projected h1
    unsigned* ebuf= (unsigned*)carve((size_t)nb * WINSLOTS * 4);         // windowed edges
    int*   csr    = (int*)  carve((size_t)nb * WINSLOTS * 4);            // windowed CSR
    // zero-region: cursor | tsum | cnt  (zeroed by k_prep)
    const int zero_words = 512 + NGRAPH * 2 + NGRAPH;
    int*   cursor = (int*)  carve(zero_words * 4);
    float* tsum   = (float*)(cursor + 512);
    int*   cnt    = (int*)  (tsum + NGRAPH * 2);
    int2*  offcnt = (int2*) carve((size_t)n * 8);
    float* dinv   = (float*)carve((size_t)n * 4);
    float* Weff   = (float*)carve(D * 2 * 4);
    float* beff   = (float*)carve(2 * 4);

    // prep (Weff/beff + zeroing) then CSR build
    k_prep<<<1, 256, 0, stream>>>(W2, Wc, b2, bc, Weff, beff, cursor, zero_words);
    k_part<<<(E + PBCHUNK - 1) / PBCHUNK, 256, 0, stream>>>(src, dst, cursor, ebuf, E, nb);
    k_csrwin<<<nb, 256, 0, stream>>>(ebuf, cursor, csr, offcnt, dinv, n);

    // layer 1 GEMM (MFMA bf16, in-kernel W1 conversion): xW1 -> bufBF
    k_gemm_mfma<<<(n + 63) / 64, 256, 0, stream>>>(x, W1, bufBF, n);
    // layer-1 agg + relu + project to z
    k_agg_proj<<<(n + 3) / 4, 256, 0, stream>>>(bufBF, offcnt, csr, dinv, b1, Weff, z, n);

    // fused layer-2 agg + mean-pool on z (raw edge stream)
    k_pool_edges<<<POOLBLK, 256, 0, stream>>>(z, src, dst, dinv, batch, tsum, cnt, n, E);
    k_classify<<<1, 128, 0, stream>>>(tsum, cnt, beff, bc, (float*)d_out);
}